// Round 5
// baseline (308.959 us; speedup 1.0000x reference)
//
#include <hip/hip_runtime.h>
#include <stdint.h>

#define NPTS 8192
#define KNN 32
#define KPN 15
#define SCC 64
#define OUTC 256
#define R2F 0.0144f              /* radius^2: the reference's in_range mask.
                                    NOTE: must be RADIUS^2, NOT EXTENT^2 —
                                    influence is dist(rel, kernel_pt) < EXT,
                                    and kernel points are offset from origin,
                                    so neighbors in (EXT, RADIUS] contribute. */
#define INV_EXT (1.0f/0.096f)
#define SCAP 128                 /* per-query survivor cap */
#define NT 8                     /* points per kpconv block */
#define COB 32                   /* rows per conv_out block */
#define QPW 4                    /* knn: queries per wave */
#define QPB 16                   /* knn: queries per block */

// ---- conv_in: 4 rows per thread (lane = channel), W read once per 4 rows ----
__global__ __launch_bounds__(256) void conv_in_k(
    const float* __restrict__ src, const float* __restrict__ tgt,
    const float* __restrict__ W, const float* __restrict__ b,
    float* __restrict__ h)
{
  int t = threadIdx.x;
  int w = t >> 6, c = t & 63;
  int row = blockIdx.x*16 + w*4;          // 0..16383 = cloud*NPTS+n (no straddle)
  const float* x = (row >> 13) ? tgt : src;
  int n0 = row & 8191;
  const float4* x0 = (const float4*)(x + (size_t)n0*256);
  const float4* x1 = x0 + 64;
  const float4* x2 = x0 + 128;
  const float4* x3 = x0 + 192;
  float bc = b[c];
  float a0 = bc, a1 = bc, a2 = bc, a3 = bc;
  #pragma unroll 4
  for (int k4 = 0; k4 < 64; ++k4) {
    float4 v0 = x0[k4], v1 = x1[k4], v2 = x2[k4], v3 = x3[k4];
    const float* wp = W + (size_t)k4*4*64 + c;
    float w0 = wp[0], w1 = wp[64], w2 = wp[128], w3 = wp[192];
    a0 = fmaf(v0.x,w0,a0); a0 = fmaf(v0.y,w1,a0); a0 = fmaf(v0.z,w2,a0); a0 = fmaf(v0.w,w3,a0);
    a1 = fmaf(v1.x,w0,a1); a1 = fmaf(v1.y,w1,a1); a1 = fmaf(v1.z,w2,a1); a1 = fmaf(v1.w,w3,a1);
    a2 = fmaf(v2.x,w0,a2); a2 = fmaf(v2.y,w1,a2); a2 = fmaf(v2.z,w2,a2); a2 = fmaf(v2.w,w3,a2);
    a3 = fmaf(v3.x,w0,a3); a3 = fmaf(v3.y,w1,a3); a3 = fmaf(v3.z,w2,a3); a3 = fmaf(v3.w,w3,a3);
  }
  float* hr = h + (size_t)row*SCC + c;
  hr[0] = a0; hr[64] = a1; hr[128] = a2; hr[192] = a3;
}

// ---- kNN v2b: 4 queries per wave, float4 LDS points, RADIUS-filtered ---------
// Each staged point is read ONCE per wave (b128) and serves 4 distance tests:
// LDS-pipe work /4 vs v1, staging traffic /4. Survivor filter at RADIUS^2 is
// exact (beyond-radius points are masked to zero influence by the reference).
__global__ __launch_bounds__(256) void knn_par(
    const float* __restrict__ cA, const float* __restrict__ cB,
    short* __restrict__ fidx)
{
  __shared__ float4 cbuf[2048];                   // 32 KB (xyz + pad)
  __shared__ unsigned long long surv[QPB][SCAP];  // 16 KB
  __shared__ unsigned int scnt[QPB];
  int b = blockIdx.x;                 // 1024 blocks: cloud(1)|qg(9)
  int cloud = b >> 9;
  int qg = b & 511;
  const float* coords = cloud ? cB : cA;
  int t = threadIdx.x;
  int w = t >> 6, lane = t & 63;
  int q0 = qg*QPB + w*QPW;            // first of this wave's 4 queries
  float qx[QPW], qy[QPW], qz[QPW];
  #pragma unroll
  for (int q = 0; q < QPW; ++q) {
    qx[q] = coords[(size_t)(q0+q)*3];
    qy[q] = coords[(size_t)(q0+q)*3+1];
    qz[q] = coords[(size_t)(q0+q)*3+2];
  }
  if (t < QPB) scnt[t] = 0u;
  for (int chunk = 0; chunk < 4; ++chunk) {
    __syncthreads();                  // cbuf reuse + (first iter) scnt publish
    int base = chunk*2048;
    for (int i = t; i < 2048; i += 256) {
      const float* p = coords + (size_t)(base+i)*3;
      cbuf[i] = make_float4(p[0], p[1], p[2], 0.f);
    }
    __syncthreads();
    #pragma unroll 4
    for (int j = 0; j < 32; ++j) {
      int i = lane + 64*j;
      float4 p = cbuf[i];
      #pragma unroll
      for (int q = 0; q < QPW; ++q) {
        float dx = qx[q]-p.x, dy = qy[q]-p.y, dz = qz[q]-p.z;
        float d2 = fmaf(dx, dx, fmaf(dy, dy, dz*dz));
        if (d2 <= R2F) {
          unsigned int pos = atomicAdd(&scnt[w*QPW+q], 1u);
          if (pos < SCAP)
            surv[w*QPW+q][pos] = ((unsigned long long)__float_as_uint(d2) << 32)
                                 | (unsigned int)(base + i);
        }
      }
    }
  }
  __syncthreads();
  #pragma unroll
  for (int q = 0; q < QPW; ++q) {
    int wq = w*QPW + q;               // wave-private: only wave w touched it
    int C = (int)scnt[wq]; if (C > SCAP) C = SCAP;
    unsigned long long k0 = (lane      < C) ? surv[wq][lane]      : ~0ULL;
    unsigned long long k1 = (lane + 64 < C) ? surv[wq][lane + 64] : ~0ULL;
    int r0 = 0, r1 = 0;
    for (int j = 0; j < C; ++j) {
      unsigned long long kj = surv[wq][j];   // same addr all lanes: broadcast
      r0 += (kj < k0);
      r1 += (kj < k1);
    }
    size_t g = (size_t)cloud*NPTS + q0 + q;
    if (k0 != ~0ULL && r0 < KNN) fidx[g*KNN + r0] = (short)(k0 & 0xffffu);
    if (k1 != ~0ULL && r1 < KNN) fidx[g*KNN + r1] = (short)(k1 & 0xffffu);
    if (lane >= C && lane < KNN) fidx[g*KNN + lane] = (short)-1;  // sentinels
  }
}

// ---- fused KPConv v3, 8 points/block, h2 out ---------------------------------
// Weights + neighbor idx live in REGISTERS, broadcast via v_readlane (no LDS).
// Phase B reads W_kp rows DIRECTLY from global (L2); K-loop barrier-free with
// depth-1 register prefetch. LDS = agg_s only (30 KB, red_s overlaid).
__global__ __launch_bounds__(512) void kpconv_fused(
    const float* __restrict__ cA, const float* __restrict__ cB,
    const float* __restrict__ kpts, const short* __restrict__ fidx,
    const float* __restrict__ h, const float* __restrict__ Wkp,
    float* __restrict__ h2)
{
  __shared__ float agg_s[NT][KPN*SCC];               // 30 KB, j = p*64+c
  float (*red_s)[NT*SCC] = (float(*)[NT*SCC])agg_s;  // 16 KB overlay (epilogue)
  int t = threadIdx.x;
  int w = t >> 6, lane = t & 63;
  int gq = blockIdx.x*NT + w;           // 0..16383 = cloud*NPTS + n
  int cloud = gq >> 13, n = gq & 8191;
  const float* coords = cloud ? cB : cA;
  int idxreg = fidx[(size_t)gq*KNN + (lane & 31)];   // lanes 32-63 mirror 0-31
  float qx = coords[(size_t)n*3];
  float qy = coords[(size_t)n*3+1];
  float qz = coords[(size_t)n*3+2];
  // weights in registers: wreg[i] = infl[k = i*4 + (lane>>4)][p = lane&15]
  int p = lane & 15;
  int pc = p < KPN ? p : 0;             // clamp: p==15 lane reads kpts[0], wv=0
  float kpx = kpts[pc*3], kpy = kpts[pc*3+1], kpz = kpts[pc*3+2];
  float wreg[8];
  #pragma unroll
  for (int i = 0; i < 8; ++i) {
    int k = i*4 + (lane >> 4);
    int idx = __shfl(idxreg, k);        // per-lane k: bpermute is fine here
    float wv = 0.f;
    if (idx >= 0 && p < KPN) {
      float rx = coords[(size_t)idx*3]   - qx;
      float ry = coords[(size_t)idx*3+1] - qy;
      float rz = coords[(size_t)idx*3+2] - qz;
      float dx = rx - kpx, dy = ry - kpy, dz = rz - kpz;
      float d = sqrtf(fmaf(dx, dx, fmaf(dy, dy, dz*dz)));
      wv = fmaxf(1.0f - d*INV_EXT, 0.0f);
    }
    wreg[i] = wv;
  }
  // Phase A: agg[p][c] for c = lane; weights broadcast via readlane (SGPR
  // FMA operand), acc[15] is a dummy. idx<0 rows have all-zero weights.
  float acc[16];
  #pragma unroll
  for (int pp = 0; pp < 16; ++pp) acc[pp] = 0.f;
  #pragma unroll
  for (int k = 0; k < KNN; ++k) {
    int idx = __builtin_amdgcn_readlane(idxreg, k);   // wave-uniform
    int ic = idx < 0 ? 0 : idx;
    float f = h[((size_t)(cloud*NPTS + ic))*SCC + lane];
    #pragma unroll
    for (int g = 0; g < 16; ++g) {
      float wg = __int_as_float(
          __builtin_amdgcn_readlane(__float_as_int(wreg[k >> 2]),
                                    ((k & 3) << 4) | g));
      acc[g] = fmaf(wg, f, acc[g]);
    }
  }
  #pragma unroll
  for (int pp = 0; pp < KPN; ++pp) agg_s[w][pp*SCC + lane] = acc[pp];
  // Phase B: h2 = agg @ Wkp. Wave w owns rows w*8..w*8+7 of each 64-row chunk,
  // read straight from global (L2-resident, each element read once per block).
  int jg = lane >> 4;            // 0..3
  int dq = (lane & 15) * 4;      // dim group
  int jbase = w*8 + jg*2;        // rows within chunk
  float4 acc4[NT];
  #pragma unroll
  for (int pt = 0; pt < NT; ++pt) acc4[pt] = make_float4(0.f,0.f,0.f,0.f);
  float4 nx0 = *(const float4*)&Wkp[(size_t)(jbase    )*SCC + dq];
  float4 nx1 = *(const float4*)&Wkp[(size_t)(jbase + 1)*SCC + dq];
  __syncthreads();               // publish agg_s (the ONLY pre-epilogue barrier)
  for (int c0 = 0; c0 < KPN*SCC; c0 += 64) {
    float4 wv0 = nx0, wv1 = nx1;
    if (c0 + 64 < KPN*SCC) {     // depth-1 prefetch of next chunk's rows
      nx0 = *(const float4*)&Wkp[(size_t)(c0 + 64 + jbase    )*SCC + dq];
      nx1 = *(const float4*)&Wkp[(size_t)(c0 + 64 + jbase + 1)*SCC + dq];
    }
    #pragma unroll
    for (int pt = 0; pt < NT; ++pt) {
      float2 av = *(const float2*)&agg_s[pt][c0 + jbase];
      acc4[pt].x = fmaf(av.x, wv0.x, acc4[pt].x);
      acc4[pt].y = fmaf(av.x, wv0.y, acc4[pt].y);
      acc4[pt].z = fmaf(av.x, wv0.z, acc4[pt].z);
      acc4[pt].w = fmaf(av.x, wv0.w, acc4[pt].w);
      acc4[pt].x = fmaf(av.y, wv1.x, acc4[pt].x);
      acc4[pt].y = fmaf(av.y, wv1.y, acc4[pt].y);
      acc4[pt].z = fmaf(av.y, wv1.z, acc4[pt].z);
      acc4[pt].w = fmaf(av.y, wv1.w, acc4[pt].w);
    }
  }
  // reduce over jg lane-groups (bits 4,5 of lane)
  #pragma unroll
  for (int pt = 0; pt < NT; ++pt) {
    acc4[pt].x += __shfl_xor(acc4[pt].x, 16); acc4[pt].x += __shfl_xor(acc4[pt].x, 32);
    acc4[pt].y += __shfl_xor(acc4[pt].y, 16); acc4[pt].y += __shfl_xor(acc4[pt].y, 32);
    acc4[pt].z += __shfl_xor(acc4[pt].z, 16); acc4[pt].z += __shfl_xor(acc4[pt].z, 32);
    acc4[pt].w += __shfl_xor(acc4[pt].w, 16); acc4[pt].w += __shfl_xor(acc4[pt].w, 32);
  }
  __syncthreads();               // all agg_s reads done -> red_s overlay safe
  if (lane < 16) {
    #pragma unroll
    for (int pt = 0; pt < NT; ++pt)
      *(float4*)&red_s[w][pt*SCC + dq] = acc4[pt];
  }
  __syncthreads();               // publish red_s
  {
    int pt = t >> 6, d = t & 63; // one h2 element per thread, coalesced store
    float s = 0.f;
    #pragma unroll
    for (int w8 = 0; w8 < NT; ++w8) s += red_s[w8][pt*SCC + d];
    h2[((size_t)blockIdx.x*NT + pt)*SCC + d] = s;
  }
}

// ---- conv_out + bias + BN partial stats: tiled GEMM, all operands in LDS -----
__global__ __launch_bounds__(512) void conv_out_bn(
    const float* __restrict__ h2, const float* __restrict__ W,
    const float* __restrict__ b, float* __restrict__ y,
    float* __restrict__ stats)
{
  __shared__ float w_s[SCC*OUTC];      // 64 KB
  __shared__ float h_s[COB][SCC];      // 8 KB
  __shared__ float rs_s[2][OUTC];      // 2 KB
  __shared__ float rs2_s[2][OUTC];     // 2 KB
  int t = threadIdx.x;
  int d = t & 255, rg = t >> 8;        // rg in {0,1}: 16-row halves
  int row0 = blockIdx.x*COB;
  int cloud = (int)(blockIdx.x >> 8);  // 256 blocks per cloud
  {
    const float4* gw = (const float4*)W;
    float4* lw = (float4*)w_s;
    #pragma unroll
    for (int i = 0; i < 8; ++i) lw[t + 512*i] = gw[t + 512*i];
    const float4* gh = (const float4*)(h2 + (size_t)row0*SCC);
    ((float4*)h_s)[t] = gh[t];
  }
  __syncthreads();
  float acc[16];
  float bb = b[d];
  #pragma unroll
  for (int r = 0; r < 16; ++r) acc[r] = bb;
  int rb = rg*16;
  #pragma unroll 4
  for (int c4 = 0; c4 < 16; ++c4) {
    float w0 = w_s[(c4*4+0)*OUTC + d];
    float w1 = w_s[(c4*4+1)*OUTC + d];
    float w2 = w_s[(c4*4+2)*OUTC + d];
    float w3 = w_s[(c4*4+3)*OUTC + d];
    #pragma unroll
    for (int r = 0; r < 16; ++r) {
      float4 hv = *(const float4*)&h_s[rb + r][c4*4];
      acc[r] = fmaf(hv.x,w0, fmaf(hv.y,w1, fmaf(hv.z,w2, fmaf(hv.w,w3, acc[r]))));
    }
  }
  float s = 0.f, s2 = 0.f;
  #pragma unroll
  for (int r = 0; r < 16; ++r) {
    float v = acc[r];
    y[((size_t)row0 + rb + r)*OUTC + d] = v;
    s += v; s2 = fmaf(v, v, s2);
  }
  rs_s[rg][d] = s; rs2_s[rg][d] = s2;
  __syncthreads();
  if (rg == 0) {
    atomicAdd(&stats[cloud*512 + d],       s  + rs_s[1][d]);
    atomicAdd(&stats[cloud*512 + 256 + d], s2 + rs2_s[1][d]);
  }
}

// ---- BN apply ----------------------------------------------------------------
__global__ __launch_bounds__(256) void bn_apply_k(
    float* __restrict__ y, const float* __restrict__ stats,
    const float* __restrict__ gamma, const float* __restrict__ beta)
{
  size_t e = (size_t)blockIdx.x*256 + threadIdx.x;
  int c = (int)(e & 255);
  int cloud = (int)(e >> 21);
  float s  = stats[cloud*512 + c];
  float s2 = stats[cloud*512 + 256 + c];
  float mu  = s * (1.0f/NPTS);
  float var = fmaxf(s2 * (1.0f/NPTS) - mu*mu, 0.f);
  float sc = gamma[c] * rsqrtf(var + 1e-5f);
  float sh = beta[c] - mu*sc;
  float v = fmaf(y[e], sc, sh);
  v = v > 0.f ? v : 0.1f*v;
  y[e] = v;
}

// ---- coords tail of output (f32) + stats zeroing (block 192) -----------------
__global__ __launch_bounds__(256) void emit_coords(
    const float* __restrict__ scd, const float* __restrict__ tcd,
    float* __restrict__ out, float* __restrict__ stats)
{
  int b = blockIdx.x;
  int t = threadIdx.x;
  if (b == 192) {
    for (int i = t; i < 1024; i += 256) stats[i] = 0.f;
    return;
  }
  int i = b*256 + t;    // 0..49151
  out[i] = (i < NPTS*3) ? scd[i] : tcd[i - NPTS*3];
}

extern "C" void kernel_launch(void* const* d_in, const int* in_sizes, int n_in,
                              void* d_out, int out_size, void* d_ws, size_t ws_size,
                              hipStream_t stream)
{
  (void)in_sizes; (void)n_in; (void)out_size; (void)ws_size;
  const float* src   = (const float*)d_in[0];
  const float* tgt   = (const float*)d_in[1];
  const float* scd   = (const float*)d_in[2];
  const float* tcd   = (const float*)d_in[3];
  const float* W_in  = (const float*)d_in[4];
  const float* b_in  = (const float*)d_in[5];
  const float* kpts  = (const float*)d_in[6];
  const float* W_kp  = (const float*)d_in[7];
  const float* W_out = (const float*)d_in[8];
  const float* b_out = (const float*)d_in[9];
  const float* gamma = (const float*)d_in[10];
  const float* beta  = (const float*)d_in[11];

  // ---- workspace ----
  char* ws = (char*)d_ws;
  float* h     = (float*)ws;                        // 0..4 MB  [2][8192][64]
  float* h2    = (float*)(ws + (4u<<20));           // 4..8 MB  [2][8192][64]
  short* fidx  = (short*)(ws + (8u<<20));           // 8..9 MB [16384][32] i16
  float* stats = (float*)(ws + (9u<<20));           // 4 KB

  float* yout = (float*)d_out;

  emit_coords<<<193, 256, 0, stream>>>(scd, tcd, yout + (size_t)2*NPTS*OUTC, stats);
  knn_par<<<1024, 256, 0, stream>>>(scd, tcd, fidx);
  conv_in_k<<<1024, 256, 0, stream>>>(src, tgt, W_in, b_in, h);
  kpconv_fused<<<2048, 512, 0, stream>>>(scd, tcd, kpts, fidx, h, W_kp, h2);
  conv_out_bn<<<512, 512, 0, stream>>>(h2, W_out, b_out, yout, stats);
  bn_apply_k<<<16384, 256, 0, stream>>>(yout, stats, gamma, beta);
}

// Round 6
// 288.118 us; speedup vs baseline: 1.0723x; 1.0723x over previous
//
#include <hip/hip_runtime.h>
#include <stdint.h>

#define NPTS 8192
#define KNN 32
#define KPN 15
#define SCC 64
#define OUTC 256
#define R2F 0.0144f              /* radius^2: the reference's in_range mask.
                                    NOTE: must be RADIUS^2, NOT EXTENT^2 —
                                    influence is dist(rel, kernel_pt) < EXT,
                                    and kernel points are offset from origin,
                                    so neighbors in (EXT, RADIUS] contribute. */
#define INV_EXT (1.0f/0.096f)
#define SCAP 128                 /* per-query survivor cap */
#define NT 8                     /* points per kpconv block */
#define COB 32                   /* rows per conv_out block */
#define QPW 4                    /* knn: queries per wave */
#define QPB 16                   /* knn: queries per block */

// ---- conv_in: 4 rows per thread (lane = channel), W read once per 4 rows ----
__global__ __launch_bounds__(256) void conv_in_k(
    const float* __restrict__ src, const float* __restrict__ tgt,
    const float* __restrict__ W, const float* __restrict__ b,
    float* __restrict__ h)
{
  int t = threadIdx.x;
  int w = t >> 6, c = t & 63;
  int row = blockIdx.x*16 + w*4;          // 0..16383 = cloud*NPTS+n (no straddle)
  const float* x = (row >> 13) ? tgt : src;
  int n0 = row & 8191;
  const float4* x0 = (const float4*)(x + (size_t)n0*256);
  const float4* x1 = x0 + 64;
  const float4* x2 = x0 + 128;
  const float4* x3 = x0 + 192;
  float bc = b[c];
  float a0 = bc, a1 = bc, a2 = bc, a3 = bc;
  #pragma unroll 4
  for (int k4 = 0; k4 < 64; ++k4) {
    float4 v0 = x0[k4], v1 = x1[k4], v2 = x2[k4], v3 = x3[k4];
    const float* wp = W + (size_t)k4*4*64 + c;
    float w0 = wp[0], w1 = wp[64], w2 = wp[128], w3 = wp[192];
    a0 = fmaf(v0.x,w0,a0); a0 = fmaf(v0.y,w1,a0); a0 = fmaf(v0.z,w2,a0); a0 = fmaf(v0.w,w3,a0);
    a1 = fmaf(v1.x,w0,a1); a1 = fmaf(v1.y,w1,a1); a1 = fmaf(v1.z,w2,a1); a1 = fmaf(v1.w,w3,a1);
    a2 = fmaf(v2.x,w0,a2); a2 = fmaf(v2.y,w1,a2); a2 = fmaf(v2.z,w2,a2); a2 = fmaf(v2.w,w3,a2);
    a3 = fmaf(v3.x,w0,a3); a3 = fmaf(v3.y,w1,a3); a3 = fmaf(v3.z,w2,a3); a3 = fmaf(v3.w,w3,a3);
  }
  float* hr = h + (size_t)row*SCC + c;
  hr[0] = a0; hr[64] = a1; hr[128] = a2; hr[192] = a3;
}

// ---- kNN v3: 4 queries/wave, coords direct from L2, ballot-compaction --------
// No coordinate staging: coords (96 KB/cloud) are L2-resident; each wave
// streams all 8192 points with coalesced dwordx3 loads. Survivor compaction
// is atomic-free: pos = running count (SGPR) + mbcnt(ballot). LDS = surv only
// (16 KB, wave-private rows) -> zero barriers, occupancy at the 32-wave cap.
__global__ __launch_bounds__(256) void knn_par(
    const float* __restrict__ cA, const float* __restrict__ cB,
    short* __restrict__ fidx)
{
  __shared__ unsigned long long surv[QPB][SCAP];  // 16 KB, wave-private rows
  int b = blockIdx.x;                 // 1024 blocks: cloud(1)|qg(9)
  int cloud = b >> 9;
  int qg = b & 511;
  const float* coords = cloud ? cB : cA;
  int t = threadIdx.x;
  int w = t >> 6, lane = t & 63;
  int q0 = qg*QPB + w*QPW;            // first of this wave's 4 queries
  float qx[QPW], qy[QPW], qz[QPW];
  #pragma unroll
  for (int q = 0; q < QPW; ++q) {
    qx[q] = coords[(size_t)(q0+q)*3];
    qy[q] = coords[(size_t)(q0+q)*3+1];
    qz[q] = coords[(size_t)(q0+q)*3+2];
  }
  unsigned int cnt[QPW] = {0u, 0u, 0u, 0u};   // wave-uniform (SGPR) counts
  #pragma unroll 2
  for (int i0 = 0; i0 < NPTS; i0 += 64) {
    int i = i0 + lane;
    const float* p = coords + (size_t)i*3;
    float px = p[0], py = p[1], pz = p[2];
    #pragma unroll
    for (int q = 0; q < QPW; ++q) {
      float dx = qx[q]-px, dy = qy[q]-py, dz = qz[q]-pz;
      float d2 = fmaf(dx, dx, fmaf(dy, dy, dz*dz));
      bool keep = (d2 <= R2F);
      unsigned long long m = __ballot(keep);
      if (keep) {
        unsigned int before = __builtin_amdgcn_mbcnt_hi(
            (unsigned int)(m >> 32),
            __builtin_amdgcn_mbcnt_lo((unsigned int)m, 0u));
        unsigned int pos = cnt[q] + before;
        if (pos < SCAP)
          surv[w*QPW+q][pos] = ((unsigned long long)__float_as_uint(d2) << 32)
                               | (unsigned int)i;
      }
      cnt[q] += (unsigned int)__popcll(m);
    }
  }
  // rank-select per query (no barrier: surv rows are wave-private; the
  // compiler's lgkmcnt waits order same-wave LDS writes before reads)
  #pragma unroll
  for (int q = 0; q < QPW; ++q) {
    int wq = w*QPW + q;
    int C = (int)cnt[q]; if (C > SCAP) C = SCAP;
    unsigned long long k0 = (lane      < C) ? surv[wq][lane]      : ~0ULL;
    unsigned long long k1 = (lane + 64 < C) ? surv[wq][lane + 64] : ~0ULL;
    int r0 = 0, r1 = 0;
    for (int j = 0; j < C; ++j) {
      unsigned long long kj = surv[wq][j];   // same addr all lanes: broadcast
      r0 += (kj < k0);
      r1 += (kj < k1);
    }
    size_t g = (size_t)cloud*NPTS + q0 + q;
    if (k0 != ~0ULL && r0 < KNN) fidx[g*KNN + r0] = (short)(k0 & 0xffffu);
    if (k1 != ~0ULL && r1 < KNN) fidx[g*KNN + r1] = (short)(k1 & 0xffffu);
    if (lane >= C && lane < KNN) fidx[g*KNN + lane] = (short)-1;  // sentinels
  }
}

// ---- fused KPConv v3, 8 points/block, h2 out ---------------------------------
// Weights + neighbor idx live in REGISTERS, broadcast via v_readlane (no LDS).
// Phase B reads W_kp rows DIRECTLY from global (L2); K-loop barrier-free with
// depth-1 register prefetch. LDS = agg_s only (30 KB, red_s overlaid).
__global__ __launch_bounds__(512) void kpconv_fused(
    const float* __restrict__ cA, const float* __restrict__ cB,
    const float* __restrict__ kpts, const short* __restrict__ fidx,
    const float* __restrict__ h, const float* __restrict__ Wkp,
    float* __restrict__ h2)
{
  __shared__ float agg_s[NT][KPN*SCC];               // 30 KB, j = p*64+c
  float (*red_s)[NT*SCC] = (float(*)[NT*SCC])agg_s;  // 16 KB overlay (epilogue)
  int t = threadIdx.x;
  int w = t >> 6, lane = t & 63;
  int gq = blockIdx.x*NT + w;           // 0..16383 = cloud*NPTS + n
  int cloud = gq >> 13, n = gq & 8191;
  const float* coords = cloud ? cB : cA;
  int idxreg = fidx[(size_t)gq*KNN + (lane & 31)];   // lanes 32-63 mirror 0-31
  float qx = coords[(size_t)n*3];
  float qy = coords[(size_t)n*3+1];
  float qz = coords[(size_t)n*3+2];
  // weights in registers: wreg[i] = infl[k = i*4 + (lane>>4)][p = lane&15]
  int p = lane & 15;
  int pc = p < KPN ? p : 0;             // clamp: p==15 lane reads kpts[0], wv=0
  float kpx = kpts[pc*3], kpy = kpts[pc*3+1], kpz = kpts[pc*3+2];
  float wreg[8];
  #pragma unroll
  for (int i = 0; i < 8; ++i) {
    int k = i*4 + (lane >> 4);
    int idx = __shfl(idxreg, k);        // per-lane k: bpermute is fine here
    float wv = 0.f;
    if (idx >= 0 && p < KPN) {
      float rx = coords[(size_t)idx*3]   - qx;
      float ry = coords[(size_t)idx*3+1] - qy;
      float rz = coords[(size_t)idx*3+2] - qz;
      float dx = rx - kpx, dy = ry - kpy, dz = rz - kpz;
      float d = sqrtf(fmaf(dx, dx, fmaf(dy, dy, dz*dz)));
      wv = fmaxf(1.0f - d*INV_EXT, 0.0f);
    }
    wreg[i] = wv;
  }
  // Phase A: agg[p][c] for c = lane; weights broadcast via readlane (SGPR
  // FMA operand), acc[15] is a dummy. idx<0 rows have all-zero weights.
  float acc[16];
  #pragma unroll
  for (int pp = 0; pp < 16; ++pp) acc[pp] = 0.f;
  #pragma unroll
  for (int k = 0; k < KNN; ++k) {
    int idx = __builtin_amdgcn_readlane(idxreg, k);   // wave-uniform
    int ic = idx < 0 ? 0 : idx;
    float f = h[((size_t)(cloud*NPTS + ic))*SCC + lane];
    #pragma unroll
    for (int g = 0; g < 16; ++g) {
      float wg = __int_as_float(
          __builtin_amdgcn_readlane(__float_as_int(wreg[k >> 2]),
                                    ((k & 3) << 4) | g));
      acc[g] = fmaf(wg, f, acc[g]);
    }
  }
  #pragma unroll
  for (int pp = 0; pp < KPN; ++pp) agg_s[w][pp*SCC + lane] = acc[pp];
  // Phase B: h2 = agg @ Wkp. Wave w owns rows w*8..w*8+7 of each 64-row chunk,
  // read straight from global (L2-resident, each element read once per block).
  int jg = lane >> 4;            // 0..3
  int dq = (lane & 15) * 4;      // dim group
  int jbase = w*8 + jg*2;        // rows within chunk
  float4 acc4[NT];
  #pragma unroll
  for (int pt = 0; pt < NT; ++pt) acc4[pt] = make_float4(0.f,0.f,0.f,0.f);
  float4 nx0 = *(const float4*)&Wkp[(size_t)(jbase    )*SCC + dq];
  float4 nx1 = *(const float4*)&Wkp[(size_t)(jbase + 1)*SCC + dq];
  __syncthreads();               // publish agg_s (the ONLY pre-epilogue barrier)
  for (int c0 = 0; c0 < KPN*SCC; c0 += 64) {
    float4 wv0 = nx0, wv1 = nx1;
    if (c0 + 64 < KPN*SCC) {     // depth-1 prefetch of next chunk's rows
      nx0 = *(const float4*)&Wkp[(size_t)(c0 + 64 + jbase    )*SCC + dq];
      nx1 = *(const float4*)&Wkp[(size_t)(c0 + 64 + jbase + 1)*SCC + dq];
    }
    #pragma unroll
    for (int pt = 0; pt < NT; ++pt) {
      float2 av = *(const float2*)&agg_s[pt][c0 + jbase];
      acc4[pt].x = fmaf(av.x, wv0.x, acc4[pt].x);
      acc4[pt].y = fmaf(av.x, wv0.y, acc4[pt].y);
      acc4[pt].z = fmaf(av.x, wv0.z, acc4[pt].z);
      acc4[pt].w = fmaf(av.x, wv0.w, acc4[pt].w);
      acc4[pt].x = fmaf(av.y, wv1.x, acc4[pt].x);
      acc4[pt].y = fmaf(av.y, wv1.y, acc4[pt].y);
      acc4[pt].z = fmaf(av.y, wv1.z, acc4[pt].z);
      acc4[pt].w = fmaf(av.y, wv1.w, acc4[pt].w);
    }
  }
  // reduce over jg lane-groups (bits 4,5 of lane)
  #pragma unroll
  for (int pt = 0; pt < NT; ++pt) {
    acc4[pt].x += __shfl_xor(acc4[pt].x, 16); acc4[pt].x += __shfl_xor(acc4[pt].x, 32);
    acc4[pt].y += __shfl_xor(acc4[pt].y, 16); acc4[pt].y += __shfl_xor(acc4[pt].y, 32);
    acc4[pt].z += __shfl_xor(acc4[pt].z, 16); acc4[pt].z += __shfl_xor(acc4[pt].z, 32);
    acc4[pt].w += __shfl_xor(acc4[pt].w, 16); acc4[pt].w += __shfl_xor(acc4[pt].w, 32);
  }
  __syncthreads();               // all agg_s reads done -> red_s overlay safe
  if (lane < 16) {
    #pragma unroll
    for (int pt = 0; pt < NT; ++pt)
      *(float4*)&red_s[w][pt*SCC + dq] = acc4[pt];
  }
  __syncthreads();               // publish red_s
  {
    int pt = t >> 6, d = t & 63; // one h2 element per thread, coalesced store
    float s = 0.f;
    #pragma unroll
    for (int w8 = 0; w8 < NT; ++w8) s += red_s[w8][pt*SCC + d];
    h2[((size_t)blockIdx.x*NT + pt)*SCC + d] = s;
  }
}

// ---- conv_out + bias + BN partial stats: tiled GEMM, all operands in LDS -----
__global__ __launch_bounds__(512) void conv_out_bn(
    const float* __restrict__ h2, const float* __restrict__ W,
    const float* __restrict__ b, float* __restrict__ y,
    float* __restrict__ stats)
{
  __shared__ float w_s[SCC*OUTC];      // 64 KB
  __shared__ float h_s[COB][SCC];      // 8 KB
  __shared__ float rs_s[2][OUTC];      // 2 KB
  __shared__ float rs2_s[2][OUTC];     // 2 KB
  int t = threadIdx.x;
  int d = t & 255, rg = t >> 8;        // rg in {0,1}: 16-row halves
  int row0 = blockIdx.x*COB;
  int cloud = (int)(blockIdx.x >> 8);  // 256 blocks per cloud
  {
    const float4* gw = (const float4*)W;
    float4* lw = (float4*)w_s;
    #pragma unroll
    for (int i = 0; i < 8; ++i) lw[t + 512*i] = gw[t + 512*i];
    const float4* gh = (const float4*)(h2 + (size_t)row0*SCC);
    ((float4*)h_s)[t] = gh[t];
  }
  __syncthreads();
  float acc[16];
  float bb = b[d];
  #pragma unroll
  for (int r = 0; r < 16; ++r) acc[r] = bb;
  int rb = rg*16;
  #pragma unroll 4
  for (int c4 = 0; c4 < 16; ++c4) {
    float w0 = w_s[(c4*4+0)*OUTC + d];
    float w1 = w_s[(c4*4+1)*OUTC + d];
    float w2 = w_s[(c4*4+2)*OUTC + d];
    float w3 = w_s[(c4*4+3)*OUTC + d];
    #pragma unroll
    for (int r = 0; r < 16; ++r) {
      float4 hv = *(const float4*)&h_s[rb + r][c4*4];
      acc[r] = fmaf(hv.x,w0, fmaf(hv.y,w1, fmaf(hv.z,w2, fmaf(hv.w,w3, acc[r]))));
    }
  }
  float s = 0.f, s2 = 0.f;
  #pragma unroll
  for (int r = 0; r < 16; ++r) {
    float v = acc[r];
    y[((size_t)row0 + rb + r)*OUTC + d] = v;
    s += v; s2 = fmaf(v, v, s2);
  }
  rs_s[rg][d] = s; rs2_s[rg][d] = s2;
  __syncthreads();
  if (rg == 0) {
    atomicAdd(&stats[cloud*512 + d],       s  + rs_s[1][d]);
    atomicAdd(&stats[cloud*512 + 256 + d], s2 + rs2_s[1][d]);
  }
}

// ---- BN apply ----------------------------------------------------------------
__global__ __launch_bounds__(256) void bn_apply_k(
    float* __restrict__ y, const float* __restrict__ stats,
    const float* __restrict__ gamma, const float* __restrict__ beta)
{
  size_t e = (size_t)blockIdx.x*256 + threadIdx.x;
  int c = (int)(e & 255);
  int cloud = (int)(e >> 21);
  float s  = stats[cloud*512 + c];
  float s2 = stats[cloud*512 + 256 + c];
  float mu  = s * (1.0f/NPTS);
  float var = fmaxf(s2 * (1.0f/NPTS) - mu*mu, 0.f);
  float sc = gamma[c] * rsqrtf(var + 1e-5f);
  float sh = beta[c] - mu*sc;
  float v = fmaf(y[e], sc, sh);
  v = v > 0.f ? v : 0.1f*v;
  y[e] = v;
}

// ---- coords tail of output (f32) + stats zeroing (block 192) -----------------
__global__ __launch_bounds__(256) void emit_coords(
    const float* __restrict__ scd, const float* __restrict__ tcd,
    float* __restrict__ out, float* __restrict__ stats)
{
  int b = blockIdx.x;
  int t = threadIdx.x;
  if (b == 192) {
    for (int i = t; i < 1024; i += 256) stats[i] = 0.f;
    return;
  }
  int i = b*256 + t;    // 0..49151
  out[i] = (i < NPTS*3) ? scd[i] : tcd[i - NPTS*3];
}

extern "C" void kernel_launch(void* const* d_in, const int* in_sizes, int n_in,
                              void* d_out, int out_size, void* d_ws, size_t ws_size,
                              hipStream_t stream)
{
  (void)in_sizes; (void)n_in; (void)out_size; (void)ws_size;
  const float* src   = (const float*)d_in[0];
  const float* tgt   = (const float*)d_in[1];
  const float* scd   = (const float*)d_in[2];
  const float* tcd   = (const float*)d_in[3];
  const float* W_in  = (const float*)d_in[4];
  const float* b_in  = (const float*)d_in[5];
  const float* kpts  = (const float*)d_in[6];
  const float* W_kp  = (const float*)d_in[7];
  const float* W_out = (const float*)d_in[8];
  const float* b_out = (const float*)d_in[9];
  const float* gamma = (const float*)d_in[10];
  const float* beta  = (const float*)d_in[11];

  // ---- workspace ----
  char* ws = (char*)d_ws;
  float* h     = (float*)ws;                        // 0..4 MB  [2][8192][64]
  float* h2    = (float*)(ws + (4u<<20));           // 4..8 MB  [2][8192][64]
  short* fidx  = (short*)(ws + (8u<<20));           // 8..9 MB [16384][32] i16
  float* stats = (float*)(ws + (9u<<20));           // 4 KB

  float* yout = (float*)d_out;

  emit_coords<<<193, 256, 0, stream>>>(scd, tcd, yout + (size_t)2*NPTS*OUTC, stats);
  knn_par<<<1024, 256, 0, stream>>>(scd, tcd, fidx);
  conv_in_k<<<1024, 256, 0, stream>>>(src, tgt, W_in, b_in, h);
  kpconv_fused<<<2048, 512, 0, stream>>>(scd, tcd, kpts, fidx, h, W_kp, h2);
  conv_out_bn<<<512, 512, 0, stream>>>(h2, W_out, b_out, yout, stats);
  bn_apply_k<<<16384, 256, 0, stream>>>(yout, stats, gamma, beta);
}

// Round 7
// 253.401 us; speedup vs baseline: 1.2192x; 1.1370x over previous
//
#include <hip/hip_runtime.h>
#include <stdint.h>

#define NPTS 8192
#define KNN 32
#define KPN 15
#define SCC 64
#define OUTC 256
#define R2F 0.0144f              /* radius^2: the reference's in_range mask.
                                    NOTE: must be RADIUS^2, NOT EXTENT^2 —
                                    influence is dist(rel, kernel_pt) < EXT,
                                    and kernel points are offset from origin,
                                    so neighbors in (EXT, RADIUS] contribute. */
#define INV_EXT (1.0f/0.096f)
#define SCAP 128                 /* per-query survivor cap */
#define NT 8                     /* points per kpconv block */
#define COB 32                   /* rows per conv_out block */
#define GD 8                     /* grid dim: cell 0.125 >= RADIUS 0.12 */
#define NCELL (GD*GD*GD)         /* 512 cells per cloud */

__device__ __forceinline__ int cell_of(float x) {
  int c = (int)(x * (float)GD);
  return c < 0 ? 0 : (c > GD-1 ? GD-1 : c);
}

// ---- conv_in: 4 rows per thread (lane = channel), W read once per 4 rows ----
__global__ __launch_bounds__(256) void conv_in_k(
    const float* __restrict__ src, const float* __restrict__ tgt,
    const float* __restrict__ W, const float* __restrict__ b,
    float* __restrict__ h)
{
  int t = threadIdx.x;
  int w = t >> 6, c = t & 63;
  int row = blockIdx.x*16 + w*4;          // 0..16383 = cloud*NPTS+n (no straddle)
  const float* x = (row >> 13) ? tgt : src;
  int n0 = row & 8191;
  const float4* x0 = (const float4*)(x + (size_t)n0*256);
  const float4* x1 = x0 + 64;
  const float4* x2 = x0 + 128;
  const float4* x3 = x0 + 192;
  float bc = b[c];
  float a0 = bc, a1 = bc, a2 = bc, a3 = bc;
  #pragma unroll 4
  for (int k4 = 0; k4 < 64; ++k4) {
    float4 v0 = x0[k4], v1 = x1[k4], v2 = x2[k4], v3 = x3[k4];
    const float* wp = W + (size_t)k4*4*64 + c;
    float w0 = wp[0], w1 = wp[64], w2 = wp[128], w3 = wp[192];
    a0 = fmaf(v0.x,w0,a0); a0 = fmaf(v0.y,w1,a0); a0 = fmaf(v0.z,w2,a0); a0 = fmaf(v0.w,w3,a0);
    a1 = fmaf(v1.x,w0,a1); a1 = fmaf(v1.y,w1,a1); a1 = fmaf(v1.z,w2,a1); a1 = fmaf(v1.w,w3,a1);
    a2 = fmaf(v2.x,w0,a2); a2 = fmaf(v2.y,w1,a2); a2 = fmaf(v2.z,w2,a2); a2 = fmaf(v2.w,w3,a2);
    a3 = fmaf(v3.x,w0,a3); a3 = fmaf(v3.y,w1,a3); a3 = fmaf(v3.z,w2,a3); a3 = fmaf(v3.w,w3,a3);
  }
  float* hr = h + (size_t)row*SCC + c;
  hr[0] = a0; hr[64] = a1; hr[128] = a2; hr[192] = a3;
}

// ---- spatial-grid build: count -> scan -> scatter ----------------------------
__global__ __launch_bounds__(256) void grid_count(
    const float* __restrict__ cA, const float* __restrict__ cB,
    unsigned int* __restrict__ hist)
{
  int i = blockIdx.x*256 + threadIdx.x;   // 0..16383
  int cloud = i >> 13, n = i & 8191;
  const float* coords = cloud ? cB : cA;
  int cx = cell_of(coords[(size_t)n*3]);
  int cy = cell_of(coords[(size_t)n*3+1]);
  int cz = cell_of(coords[(size_t)n*3+2]);
  atomicAdd(&hist[cloud*NCELL + (cz*GD + cy)*GD + cx], 1u);
}

__global__ __launch_bounds__(512) void grid_scan(
    const unsigned int* __restrict__ hist,
    unsigned int* __restrict__ starts,     // [2][520], [512] = total
    unsigned int* __restrict__ cursor)     // [2][512]
{
  __shared__ unsigned int a[NCELL], b[NCELL];
  int t = threadIdx.x;
  for (int cloud = 0; cloud < 2; ++cloud) {
    unsigned int v = hist[cloud*NCELL + t];
    a[t] = v; __syncthreads();
    unsigned int *src = a, *dst = b;
    for (int off = 1; off < NCELL; off <<= 1) {
      unsigned int x = src[t];
      if (t >= off) x += src[t - off];
      dst[t] = x; __syncthreads();
      unsigned int* tmp = src; src = dst; dst = tmp;
    }
    unsigned int inc = src[t];
    unsigned int exc = inc - v;
    starts[cloud*520 + t] = exc;
    cursor[cloud*NCELL + t] = exc;
    if (t == NCELL-1) starts[cloud*520 + NCELL] = inc;   // = 8192
    __syncthreads();
  }
}

__global__ __launch_bounds__(256) void grid_scatter(
    const float* __restrict__ cA, const float* __restrict__ cB,
    unsigned int* __restrict__ cursor, float4* __restrict__ sorted)
{
  int i = blockIdx.x*256 + threadIdx.x;   // 0..16383
  int cloud = i >> 13, n = i & 8191;
  const float* coords = cloud ? cB : cA;
  float x = coords[(size_t)n*3], y = coords[(size_t)n*3+1], z = coords[(size_t)n*3+2];
  int cell = (cell_of(z)*GD + cell_of(y))*GD + cell_of(x);
  unsigned int slot = atomicAdd(&cursor[cloud*NCELL + cell], 1u);
  sorted[(size_t)cloud*NPTS + slot] = make_float4(x, y, z, __int_as_float(n));
}

// ---- kNN v4: spatial grid, one wave per query --------------------------------
// 27 neighbor cells = 9 contiguous sorted ranges (x fastest-varying) ~432
// candidates vs 8192 brute-force. Ballot-compaction of survivors; identical
// key/rank-select/sentinel semantics to the verified brute-force version
// (keys (d2<<32)|origIdx are distinct: ties broken by index = top_k order).
__global__ __launch_bounds__(256) void knn_grid(
    const float* __restrict__ cA, const float* __restrict__ cB,
    const unsigned int* __restrict__ starts, const float4* __restrict__ sorted,
    short* __restrict__ fidx)
{
  __shared__ unsigned long long surv[4][SCAP];   // 4 KB, wave-private rows
  int t = threadIdx.x, w = t >> 6, lane = t & 63;
  int q = blockIdx.x*4 + w;            // 0..16383
  int cloud = q >> 13, n = q & 8191;
  const float* coords = cloud ? cB : cA;
  float qx = coords[(size_t)n*3];
  float qy = coords[(size_t)n*3+1];
  float qz = coords[(size_t)n*3+2];
  int cx = cell_of(qx), cy = cell_of(qy), cz = cell_of(qz);
  const unsigned int* st = starts + cloud*520;
  const float4* sp = sorted + (size_t)cloud*NPTS;
  int c0 = cx > 0 ? cx-1 : 0;
  int c1 = cx < GD-1 ? cx+1 : GD-1;
  unsigned int cnt = 0;
  for (int dz = -1; dz <= 1; ++dz) {
    int zz = cz + dz; if (zz < 0 || zz > GD-1) continue;
    for (int dy = -1; dy <= 1; ++dy) {
      int yy = cy + dy; if (yy < 0 || yy > GD-1) continue;
      int rb = (zz*GD + yy)*GD;
      unsigned int s = st[rb + c0];
      unsigned int e = st[rb + c1 + 1];
      for (unsigned int jj = s; jj < e; jj += 64) {
        unsigned int j = jj + lane;
        bool keep = false; float d2 = 0.f; unsigned int oi = 0;
        if (j < e) {
          float4 p = sp[j];
          float dx = qx-p.x, dyy = qy-p.y, dzz = qz-p.z;
          d2 = fmaf(dx, dx, fmaf(dyy, dyy, dzz*dzz));
          oi = __float_as_uint(p.w);
          keep = (d2 <= R2F);
        }
        unsigned long long m = __ballot(keep);
        if (keep) {
          unsigned int before = __builtin_amdgcn_mbcnt_hi(
              (unsigned int)(m >> 32),
              __builtin_amdgcn_mbcnt_lo((unsigned int)m, 0u));
          unsigned int pos = cnt + before;
          if (pos < SCAP)
            surv[w][pos] = ((unsigned long long)__float_as_uint(d2) << 32) | oi;
        }
        cnt += (unsigned int)__popcll(m);
      }
    }
  }
  // rank-select (surv row is wave-private; same-wave LDS ordering via lgkmcnt)
  int C = (int)cnt; if (C > SCAP) C = SCAP;
  unsigned long long k0 = (lane      < C) ? surv[w][lane]      : ~0ULL;
  unsigned long long k1 = (lane + 64 < C) ? surv[w][lane + 64] : ~0ULL;
  int r0 = 0, r1 = 0;
  for (int j = 0; j < C; ++j) {
    unsigned long long kj = surv[w][j];      // same addr all lanes: broadcast
    r0 += (kj < k0);
    r1 += (kj < k1);
  }
  size_t g = (size_t)cloud*NPTS + n;
  if (k0 != ~0ULL && r0 < KNN) fidx[g*KNN + r0] = (short)(k0 & 0xffffu);
  if (k1 != ~0ULL && r1 < KNN) fidx[g*KNN + r1] = (short)(k1 & 0xffffu);
  if (lane >= C && lane < KNN) fidx[g*KNN + lane] = (short)-1;   // sentinels
}

// ---- fused KPConv v3, 8 points/block, h2 out ---------------------------------
// Weights + neighbor idx live in REGISTERS, broadcast via v_readlane (no LDS).
// Phase B reads W_kp rows DIRECTLY from global (L2); K-loop barrier-free with
// depth-1 register prefetch. LDS = agg_s only (30 KB, red_s overlaid).
__global__ __launch_bounds__(512) void kpconv_fused(
    const float* __restrict__ cA, const float* __restrict__ cB,
    const float* __restrict__ kpts, const short* __restrict__ fidx,
    const float* __restrict__ h, const float* __restrict__ Wkp,
    float* __restrict__ h2)
{
  __shared__ float agg_s[NT][KPN*SCC];               // 30 KB, j = p*64+c
  float (*red_s)[NT*SCC] = (float(*)[NT*SCC])agg_s;  // 16 KB overlay (epilogue)
  int t = threadIdx.x;
  int w = t >> 6, lane = t & 63;
  int gq = blockIdx.x*NT + w;           // 0..16383 = cloud*NPTS + n
  int cloud = gq >> 13, n = gq & 8191;
  const float* coords = cloud ? cB : cA;
  int idxreg = fidx[(size_t)gq*KNN + (lane & 31)];   // lanes 32-63 mirror 0-31
  float qx = coords[(size_t)n*3];
  float qy = coords[(size_t)n*3+1];
  float qz = coords[(size_t)n*3+2];
  // weights in registers: wreg[i] = infl[k = i*4 + (lane>>4)][p = lane&15]
  int p = lane & 15;
  int pc = p < KPN ? p : 0;             // clamp: p==15 lane reads kpts[0], wv=0
  float kpx = kpts[pc*3], kpy = kpts[pc*3+1], kpz = kpts[pc*3+2];
  float wreg[8];
  #pragma unroll
  for (int i = 0; i < 8; ++i) {
    int k = i*4 + (lane >> 4);
    int idx = __shfl(idxreg, k);        // per-lane k: bpermute is fine here
    float wv = 0.f;
    if (idx >= 0 && p < KPN) {
      float rx = coords[(size_t)idx*3]   - qx;
      float ry = coords[(size_t)idx*3+1] - qy;
      float rz = coords[(size_t)idx*3+2] - qz;
      float dx = rx - kpx, dy = ry - kpy, dz = rz - kpz;
      float d = sqrtf(fmaf(dx, dx, fmaf(dy, dy, dz*dz)));
      wv = fmaxf(1.0f - d*INV_EXT, 0.0f);
    }
    wreg[i] = wv;
  }
  // Phase A: agg[p][c] for c = lane; weights broadcast via readlane (SGPR
  // FMA operand), acc[15] is a dummy. idx<0 rows have all-zero weights.
  float acc[16];
  #pragma unroll
  for (int pp = 0; pp < 16; ++pp) acc[pp] = 0.f;
  #pragma unroll
  for (int k = 0; k < KNN; ++k) {
    int idx = __builtin_amdgcn_readlane(idxreg, k);   // wave-uniform
    int ic = idx < 0 ? 0 : idx;
    float f = h[((size_t)(cloud*NPTS + ic))*SCC + lane];
    #pragma unroll
    for (int g = 0; g < 16; ++g) {
      float wg = __int_as_float(
          __builtin_amdgcn_readlane(__float_as_int(wreg[k >> 2]),
                                    ((k & 3) << 4) | g));
      acc[g] = fmaf(wg, f, acc[g]);
    }
  }
  #pragma unroll
  for (int pp = 0; pp < KPN; ++pp) agg_s[w][pp*SCC + lane] = acc[pp];
  // Phase B: h2 = agg @ Wkp. Wave w owns rows w*8..w*8+7 of each 64-row chunk,
  // read straight from global (L2-resident, each element read once per block).
  int jg = lane >> 4;            // 0..3
  int dq = (lane & 15) * 4;      // dim group
  int jbase = w*8 + jg*2;        // rows within chunk
  float4 acc4[NT];
  #pragma unroll
  for (int pt = 0; pt < NT; ++pt) acc4[pt] = make_float4(0.f,0.f,0.f,0.f);
  float4 nx0 = *(const float4*)&Wkp[(size_t)(jbase    )*SCC + dq];
  float4 nx1 = *(const float4*)&Wkp[(size_t)(jbase + 1)*SCC + dq];
  __syncthreads();               // publish agg_s (the ONLY pre-epilogue barrier)
  for (int c0 = 0; c0 < KPN*SCC; c0 += 64) {
    float4 wv0 = nx0, wv1 = nx1;
    if (c0 + 64 < KPN*SCC) {     // depth-1 prefetch of next chunk's rows
      nx0 = *(const float4*)&Wkp[(size_t)(c0 + 64 + jbase    )*SCC + dq];
      nx1 = *(const float4*)&Wkp[(size_t)(c0 + 64 + jbase + 1)*SCC + dq];
    }
    #pragma unroll
    for (int pt = 0; pt < NT; ++pt) {
      float2 av = *(const float2*)&agg_s[pt][c0 + jbase];
      acc4[pt].x = fmaf(av.x, wv0.x, acc4[pt].x);
      acc4[pt].y = fmaf(av.x, wv0.y, acc4[pt].y);
      acc4[pt].z = fmaf(av.x, wv0.z, acc4[pt].z);
      acc4[pt].w = fmaf(av.x, wv0.w, acc4[pt].w);
      acc4[pt].x = fmaf(av.y, wv1.x, acc4[pt].x);
      acc4[pt].y = fmaf(av.y, wv1.y, acc4[pt].y);
      acc4[pt].z = fmaf(av.y, wv1.z, acc4[pt].z);
      acc4[pt].w = fmaf(av.y, wv1.w, acc4[pt].w);
    }
  }
  // reduce over jg lane-groups (bits 4,5 of lane)
  #pragma unroll
  for (int pt = 0; pt < NT; ++pt) {
    acc4[pt].x += __shfl_xor(acc4[pt].x, 16); acc4[pt].x += __shfl_xor(acc4[pt].x, 32);
    acc4[pt].y += __shfl_xor(acc4[pt].y, 16); acc4[pt].y += __shfl_xor(acc4[pt].y, 32);
    acc4[pt].z += __shfl_xor(acc4[pt].z, 16); acc4[pt].z += __shfl_xor(acc4[pt].z, 32);
    acc4[pt].w += __shfl_xor(acc4[pt].w, 16); acc4[pt].w += __shfl_xor(acc4[pt].w, 32);
  }
  __syncthreads();               // all agg_s reads done -> red_s overlay safe
  if (lane < 16) {
    #pragma unroll
    for (int pt = 0; pt < NT; ++pt)
      *(float4*)&red_s[w][pt*SCC + dq] = acc4[pt];
  }
  __syncthreads();               // publish red_s
  {
    int pt = t >> 6, d = t & 63; // one h2 element per thread, coalesced store
    float s = 0.f;
    #pragma unroll
    for (int w8 = 0; w8 < NT; ++w8) s += red_s[w8][pt*SCC + d];
    h2[((size_t)blockIdx.x*NT + pt)*SCC + d] = s;
  }
}

// ---- conv_out + bias + BN partial stats: tiled GEMM, all operands in LDS -----
__global__ __launch_bounds__(512) void conv_out_bn(
    const float* __restrict__ h2, const float* __restrict__ W,
    const float* __restrict__ b, float* __restrict__ y,
    float* __restrict__ stats)
{
  __shared__ float w_s[SCC*OUTC];      // 64 KB
  __shared__ float h_s[COB][SCC];      // 8 KB
  __shared__ float rs_s[2][OUTC];      // 2 KB
  __shared__ float rs2_s[2][OUTC];     // 2 KB
  int t = threadIdx.x;
  int d = t & 255, rg = t >> 8;        // rg in {0,1}: 16-row halves
  int row0 = blockIdx.x*COB;
  int cloud = (int)(blockIdx.x >> 8);  // 256 blocks per cloud
  {
    const float4* gw = (const float4*)W;
    float4* lw = (float4*)w_s;
    #pragma unroll
    for (int i = 0; i < 8; ++i) lw[t + 512*i] = gw[t + 512*i];
    const float4* gh = (const float4*)(h2 + (size_t)row0*SCC);
    ((float4*)h_s)[t] = gh[t];
  }
  __syncthreads();
  float acc[16];
  float bb = b[d];
  #pragma unroll
  for (int r = 0; r < 16; ++r) acc[r] = bb;
  int rb = rg*16;
  #pragma unroll 4
  for (int c4 = 0; c4 < 16; ++c4) {
    float w0 = w_s[(c4*4+0)*OUTC + d];
    float w1 = w_s[(c4*4+1)*OUTC + d];
    float w2 = w_s[(c4*4+2)*OUTC + d];
    float w3 = w_s[(c4*4+3)*OUTC + d];
    #pragma unroll
    for (int r = 0; r < 16; ++r) {
      float4 hv = *(const float4*)&h_s[rb + r][c4*4];
      acc[r] = fmaf(hv.x,w0, fmaf(hv.y,w1, fmaf(hv.z,w2, fmaf(hv.w,w3, acc[r]))));
    }
  }
  float s = 0.f, s2 = 0.f;
  #pragma unroll
  for (int r = 0; r < 16; ++r) {
    float v = acc[r];
    y[((size_t)row0 + rb + r)*OUTC + d] = v;
    s += v; s2 = fmaf(v, v, s2);
  }
  rs_s[rg][d] = s; rs2_s[rg][d] = s2;
  __syncthreads();
  if (rg == 0) {
    atomicAdd(&stats[cloud*512 + d],       s  + rs_s[1][d]);
    atomicAdd(&stats[cloud*512 + 256 + d], s2 + rs2_s[1][d]);
  }
}

// ---- BN apply ----------------------------------------------------------------
__global__ __launch_bounds__(256) void bn_apply_k(
    float* __restrict__ y, const float* __restrict__ stats,
    const float* __restrict__ gamma, const float* __restrict__ beta)
{
  size_t e = (size_t)blockIdx.x*256 + threadIdx.x;
  int c = (int)(e & 255);
  int cloud = (int)(e >> 21);
  float s  = stats[cloud*512 + c];
  float s2 = stats[cloud*512 + 256 + c];
  float mu  = s * (1.0f/NPTS);
  float var = fmaxf(s2 * (1.0f/NPTS) - mu*mu, 0.f);
  float sc = gamma[c] * rsqrtf(var + 1e-5f);
  float sh = beta[c] - mu*sc;
  float v = fmaf(y[e], sc, sh);
  v = v > 0.f ? v : 0.1f*v;
  y[e] = v;
}

// ---- coords tail of output (f32) + stats/hist zeroing (block 192) ------------
__global__ __launch_bounds__(256) void emit_coords(
    const float* __restrict__ scd, const float* __restrict__ tcd,
    float* __restrict__ out, float* __restrict__ stats,
    unsigned int* __restrict__ hist)
{
  int b = blockIdx.x;
  int t = threadIdx.x;
  if (b == 192) {
    for (int i = t; i < 1024; i += 256) { stats[i] = 0.f; hist[i] = 0u; }
    return;
  }
  int i = b*256 + t;    // 0..49151
  out[i] = (i < NPTS*3) ? scd[i] : tcd[i - NPTS*3];
}

extern "C" void kernel_launch(void* const* d_in, const int* in_sizes, int n_in,
                              void* d_out, int out_size, void* d_ws, size_t ws_size,
                              hipStream_t stream)
{
  (void)in_sizes; (void)n_in; (void)out_size; (void)ws_size;
  const float* src   = (const float*)d_in[0];
  const float* tgt   = (const float*)d_in[1];
  const float* scd   = (const float*)d_in[2];
  const float* tcd   = (const float*)d_in[3];
  const float* W_in  = (const float*)d_in[4];
  const float* b_in  = (const float*)d_in[5];
  const float* kpts  = (const float*)d_in[6];
  const float* W_kp  = (const float*)d_in[7];
  const float* W_out = (const float*)d_in[8];
  const float* b_out = (const float*)d_in[9];
  const float* gamma = (const float*)d_in[10];
  const float* beta  = (const float*)d_in[11];

  // ---- workspace ----
  char* ws = (char*)d_ws;
  float* h     = (float*)ws;                        // 0..4 MB  [2][8192][64]
  float* h2    = (float*)(ws + (4u<<20));           // 4..8 MB  [2][8192][64]
  short* fidx  = (short*)(ws + (8u<<20));           // 8..9 MB [16384][32] i16
  float* stats = (float*)(ws + (9u<<20));           // 4 KB
  // grid aux lives INSIDE the h2 region: dead before kpconv's first h2 write
  // (kpconv fully overwrites h2), and rebuilt from scratch every launch.
  unsigned int* hist   = (unsigned int*)(ws + (4u<<20));            // 4 KB
  unsigned int* starts = (unsigned int*)(ws + (4u<<20) + (8u<<10)); // 2x520 u32
  unsigned int* cursor = (unsigned int*)(ws + (4u<<20) + (16u<<10));// 4 KB
  float4* sorted       = (float4*)(ws + (4u<<20) + (32u<<10));      // 256 KB

  float* yout = (float*)d_out;

  emit_coords<<<193, 256, 0, stream>>>(scd, tcd, yout + (size_t)2*NPTS*OUTC,
                                       stats, hist);
  grid_count<<<64, 256, 0, stream>>>(scd, tcd, hist);
  grid_scan<<<1, 512, 0, stream>>>(hist, starts, cursor);
  grid_scatter<<<64, 256, 0, stream>>>(scd, tcd, cursor, sorted);
  knn_grid<<<4096, 256, 0, stream>>>(scd, tcd, starts, sorted, fidx);
  conv_in_k<<<1024, 256, 0, stream>>>(src, tgt, W_in, b_in, h);
  kpconv_fused<<<2048, 512, 0, stream>>>(scd, tcd, kpts, fidx, h, W_kp, h2);
  conv_out_bn<<<512, 512, 0, stream>>>(h2, W_out, b_out, yout, stats);
  bn_apply_k<<<16384, 256, 0, stream>>>(yout, stats, gamma, beta);
}

// Round 8
// 243.415 us; speedup vs baseline: 1.2693x; 1.0410x over previous
//
#include <hip/hip_runtime.h>
#include <stdint.h>

#define NPTS 8192
#define KNN 32
#define KPN 15
#define SCC 64
#define OUTC 256
#define R2F 0.0144f              /* radius^2: the reference's in_range mask.
                                    NOTE: must be RADIUS^2, NOT EXTENT^2 —
                                    influence is dist(rel, kernel_pt) < EXT,
                                    and kernel points are offset from origin,
                                    so neighbors in (EXT, RADIUS] contribute. */
#define INV_EXT (1.0f/0.096f)
#define SCAP 128                 /* per-query survivor cap */
#define NT 8                     /* points per kpconv block */
#define COB 32                   /* rows per conv_out block */
#define GD 8                     /* grid dim: cell 0.125 >= RADIUS 0.12 */
#define NCELL (GD*GD*GD)         /* 512 cells per cloud */

typedef float  f32x4  __attribute__((ext_vector_type(4)));
typedef __bf16 bf16x8 __attribute__((ext_vector_type(8)));

__device__ __forceinline__ int cell_of(float x) {
  int c = (int)(x * (float)GD);
  return c < 0 ? 0 : (c > GD-1 ? GD-1 : c);
}

// ---- conv_in: 4 rows per thread (lane = channel), W read once per 4 rows ----
__global__ __launch_bounds__(256) void conv_in_k(
    const float* __restrict__ src, const float* __restrict__ tgt,
    const float* __restrict__ W, const float* __restrict__ b,
    float* __restrict__ h)
{
  int t = threadIdx.x;
  int w = t >> 6, c = t & 63;
  int row = blockIdx.x*16 + w*4;          // 0..16383 = cloud*NPTS+n (no straddle)
  const float* x = (row >> 13) ? tgt : src;
  int n0 = row & 8191;
  const float4* x0 = (const float4*)(x + (size_t)n0*256);
  const float4* x1 = x0 + 64;
  const float4* x2 = x0 + 128;
  const float4* x3 = x0 + 192;
  float bc = b[c];
  float a0 = bc, a1 = bc, a2 = bc, a3 = bc;
  #pragma unroll 4
  for (int k4 = 0; k4 < 64; ++k4) {
    float4 v0 = x0[k4], v1 = x1[k4], v2 = x2[k4], v3 = x3[k4];
    const float* wp = W + (size_t)k4*4*64 + c;
    float w0 = wp[0], w1 = wp[64], w2 = wp[128], w3 = wp[192];
    a0 = fmaf(v0.x,w0,a0); a0 = fmaf(v0.y,w1,a0); a0 = fmaf(v0.z,w2,a0); a0 = fmaf(v0.w,w3,a0);
    a1 = fmaf(v1.x,w0,a1); a1 = fmaf(v1.y,w1,a1); a1 = fmaf(v1.z,w2,a1); a1 = fmaf(v1.w,w3,a1);
    a2 = fmaf(v2.x,w0,a2); a2 = fmaf(v2.y,w1,a2); a2 = fmaf(v2.z,w2,a2); a2 = fmaf(v2.w,w3,a2);
    a3 = fmaf(v3.x,w0,a3); a3 = fmaf(v3.y,w1,a3); a3 = fmaf(v3.z,w2,a3); a3 = fmaf(v3.w,w3,a3);
  }
  float* hr = h + (size_t)row*SCC + c;
  hr[0] = a0; hr[64] = a1; hr[128] = a2; hr[192] = a3;
}

// ---- spatial-grid build: count -> scan -> scatter ----------------------------
__global__ __launch_bounds__(256) void grid_count(
    const float* __restrict__ cA, const float* __restrict__ cB,
    unsigned int* __restrict__ hist)
{
  int i = blockIdx.x*256 + threadIdx.x;   // 0..16383
  int cloud = i >> 13, n = i & 8191;
  const float* coords = cloud ? cB : cA;
  int cx = cell_of(coords[(size_t)n*3]);
  int cy = cell_of(coords[(size_t)n*3+1]);
  int cz = cell_of(coords[(size_t)n*3+2]);
  atomicAdd(&hist[cloud*NCELL + (cz*GD + cy)*GD + cx], 1u);
}

__global__ __launch_bounds__(512) void grid_scan(
    const unsigned int* __restrict__ hist,
    unsigned int* __restrict__ starts,     // [2][520], [512] = total
    unsigned int* __restrict__ cursor)     // [2][512]
{
  __shared__ unsigned int a[NCELL], b[NCELL];
  int t = threadIdx.x;
  for (int cloud = 0; cloud < 2; ++cloud) {
    unsigned int v = hist[cloud*NCELL + t];
    a[t] = v; __syncthreads();
    unsigned int *src = a, *dst = b;
    for (int off = 1; off < NCELL; off <<= 1) {
      unsigned int x = src[t];
      if (t >= off) x += src[t - off];
      dst[t] = x; __syncthreads();
      unsigned int* tmp = src; src = dst; dst = tmp;
    }
    unsigned int inc = src[t];
    unsigned int exc = inc - v;
    starts[cloud*520 + t] = exc;
    cursor[cloud*NCELL + t] = exc;
    if (t == NCELL-1) starts[cloud*520 + NCELL] = inc;   // = 8192
    __syncthreads();
  }
}

__global__ __launch_bounds__(256) void grid_scatter(
    const float* __restrict__ cA, const float* __restrict__ cB,
    unsigned int* __restrict__ cursor, float4* __restrict__ sorted)
{
  int i = blockIdx.x*256 + threadIdx.x;   // 0..16383
  int cloud = i >> 13, n = i & 8191;
  const float* coords = cloud ? cB : cA;
  float x = coords[(size_t)n*3], y = coords[(size_t)n*3+1], z = coords[(size_t)n*3+2];
  int cell = (cell_of(z)*GD + cell_of(y))*GD + cell_of(x);
  unsigned int slot = atomicAdd(&cursor[cloud*NCELL + cell], 1u);
  sorted[(size_t)cloud*NPTS + slot] = make_float4(x, y, z, __int_as_float(n));
}

// ---- kNN v4: spatial grid, one wave per query --------------------------------
// 27 neighbor cells = 9 contiguous sorted ranges (x fastest-varying) ~432
// candidates vs 8192 brute-force. Ballot-compaction of survivors; identical
// key/rank-select/sentinel semantics to the verified brute-force version.
__global__ __launch_bounds__(256) void knn_grid(
    const float* __restrict__ cA, const float* __restrict__ cB,
    const unsigned int* __restrict__ starts, const float4* __restrict__ sorted,
    short* __restrict__ fidx)
{
  __shared__ unsigned long long surv[4][SCAP];   // 4 KB, wave-private rows
  int t = threadIdx.x, w = t >> 6, lane = t & 63;
  int q = blockIdx.x*4 + w;            // 0..16383
  int cloud = q >> 13, n = q & 8191;
  const float* coords = cloud ? cB : cA;
  float qx = coords[(size_t)n*3];
  float qy = coords[(size_t)n*3+1];
  float qz = coords[(size_t)n*3+2];
  int cx = cell_of(qx), cy = cell_of(qy), cz = cell_of(qz);
  const unsigned int* st = starts + cloud*520;
  const float4* sp = sorted + (size_t)cloud*NPTS;
  int c0 = cx > 0 ? cx-1 : 0;
  int c1 = cx < GD-1 ? cx+1 : GD-1;
  unsigned int cnt = 0;
  for (int dz = -1; dz <= 1; ++dz) {
    int zz = cz + dz; if (zz < 0 || zz > GD-1) continue;
    for (int dy = -1; dy <= 1; ++dy) {
      int yy = cy + dy; if (yy < 0 || yy > GD-1) continue;
      int rb = (zz*GD + yy)*GD;
      unsigned int s = st[rb + c0];
      unsigned int e = st[rb + c1 + 1];
      for (unsigned int jj = s; jj < e; jj += 64) {
        unsigned int j = jj + lane;
        bool keep = false; float d2 = 0.f; unsigned int oi = 0;
        if (j < e) {
          float4 p = sp[j];
          float dx = qx-p.x, dyy = qy-p.y, dzz = qz-p.z;
          d2 = fmaf(dx, dx, fmaf(dyy, dyy, dzz*dzz));
          oi = __float_as_uint(p.w);
          keep = (d2 <= R2F);
        }
        unsigned long long m = __ballot(keep);
        if (keep) {
          unsigned int before = __builtin_amdgcn_mbcnt_hi(
              (unsigned int)(m >> 32),
              __builtin_amdgcn_mbcnt_lo((unsigned int)m, 0u));
          unsigned int pos = cnt + before;
          if (pos < SCAP)
            surv[w][pos] = ((unsigned long long)__float_as_uint(d2) << 32) | oi;
        }
        cnt += (unsigned int)__popcll(m);
      }
    }
  }
  // rank-select (surv row is wave-private; same-wave LDS ordering via lgkmcnt)
  int C = (int)cnt; if (C > SCAP) C = SCAP;
  unsigned long long k0 = (lane      < C) ? surv[w][lane]      : ~0ULL;
  unsigned long long k1 = (lane + 64 < C) ? surv[w][lane + 64] : ~0ULL;
  int r0 = 0, r1 = 0;
  for (int j = 0; j < C; ++j) {
    unsigned long long kj = surv[w][j];      // same addr all lanes: broadcast
    r0 += (kj < k0);
    r1 += (kj < k1);
  }
  size_t g = (size_t)cloud*NPTS + n;
  if (k0 != ~0ULL && r0 < KNN) fidx[g*KNN + r0] = (short)(k0 & 0xffffu);
  if (k1 != ~0ULL && r1 < KNN) fidx[g*KNN + r1] = (short)(k1 & 0xffffu);
  if (lane >= C && lane < KNN) fidx[g*KNN + lane] = (short)-1;   // sentinels
}

// ---- fused KPConv v4: MFMA Phase A, 8 points/block, h2 out -------------------
// Phase A per point: agg(15x64) = w(15x32) @ h_gather(32x64) via FOUR
// mfma_f32_16x16x32_bf16 (K=32 in one instruction, 16-ch tiles). Each lane
// computes its A-slot (p=lane&15, k=(lane>>4)*8+j) directly — no repacking.
// Correctness is invariant to the exact (lane,j)->k HW mapping because A and
// B use the SAME mapping (shared k-permutation cancels in the dot product);
// the C/D layout used for stores is HW-verified: col=lane&15,
// row=(lane>>4)*4+reg. Phase B unchanged (fp32 VALU, global-L2 Wkp).
__global__ __launch_bounds__(512) void kpconv_fused(
    const float* __restrict__ cA, const float* __restrict__ cB,
    const float* __restrict__ kpts, const short* __restrict__ fidx,
    const float* __restrict__ h, const float* __restrict__ Wkp,
    float* __restrict__ h2)
{
  __shared__ float agg_s[NT][KPN*SCC];               // 30 KB, j = p*64+c
  float (*red_s)[NT*SCC] = (float(*)[NT*SCC])agg_s;  // 16 KB overlay (epilogue)
  int t = threadIdx.x;
  int w = t >> 6, lane = t & 63;
  int gq = blockIdx.x*NT + w;           // 0..16383 = cloud*NPTS + n
  int cloud = gq >> 13, n = gq & 8191;
  const float* coords = cloud ? cB : cA;
  int idxreg = fidx[(size_t)gq*KNN + (lane & 31)];   // lanes 32-63 mirror 0-31
  float qx = coords[(size_t)n*3];
  float qy = coords[(size_t)n*3+1];
  float qz = coords[(size_t)n*3+2];
  int g16 = lane >> 4;                  // k-group: this lane covers k=g16*8+j
  int p   = lane & 15;                  // A-row (kernel point) and B/D column
  int pc  = p < KPN ? p : 0;            // clamp: p==15 row is zero-weighted
  float kpx = kpts[pc*3], kpy = kpts[pc*3+1], kpz = kpts[pc*3+2];
  // A-fragment: w[p][k] in bf16; remember clamped idx per j for the gather.
  bf16x8 afrag;
  int idxs[8];
  #pragma unroll
  for (int j = 0; j < 8; ++j) {
    int k = g16*8 + j;
    int idx = __shfl(idxreg, k);        // idx for neighbor k (lanes 0-31 hold)
    idxs[j] = idx < 0 ? 0 : idx;
    float wv = 0.f;
    if (idx >= 0 && p < KPN) {
      float rx = coords[(size_t)idx*3]   - qx;
      float ry = coords[(size_t)idx*3+1] - qy;
      float rz = coords[(size_t)idx*3+2] - qz;
      float dx = rx - kpx, dy = ry - kpy, dz = rz - kpz;
      float d = sqrtf(fmaf(dx, dx, fmaf(dy, dy, dz*dz)));
      wv = fmaxf(1.0f - d*INV_EXT, 0.0f);
    }
    afrag[j] = (__bf16)wv;              // idx<0 -> 0: zero A kills garbage B
  }
  // B-fragments: h[idx_k][ct*16 + p], 4 channel tiles, converted to bf16.
  bf16x8 bfrag0, bfrag1, bfrag2, bfrag3;
  #pragma unroll
  for (int j = 0; j < 8; ++j) {
    const float* hrow = h + ((size_t)(cloud*NPTS + idxs[j]))*SCC + p;
    bfrag0[j] = (__bf16)hrow[0];
    bfrag1[j] = (__bf16)hrow[16];
    bfrag2[j] = (__bf16)hrow[32];
    bfrag3[j] = (__bf16)hrow[48];
  }
  f32x4 acc0 = {0.f,0.f,0.f,0.f}, acc1 = acc0, acc2 = acc0, acc3 = acc0;
  acc0 = __builtin_amdgcn_mfma_f32_16x16x32_bf16(afrag, bfrag0, acc0, 0, 0, 0);
  acc1 = __builtin_amdgcn_mfma_f32_16x16x32_bf16(afrag, bfrag1, acc1, 0, 0, 0);
  acc2 = __builtin_amdgcn_mfma_f32_16x16x32_bf16(afrag, bfrag2, acc2, 0, 0, 0);
  acc3 = __builtin_amdgcn_mfma_f32_16x16x32_bf16(afrag, bfrag3, acc3, 0, 0, 0);
  // Store D: row pp=(lane>>4)*4+r, col ct*16+p (HW-verified C/D layout).
  #pragma unroll
  for (int r = 0; r < 4; ++r) {
    int pp = g16*4 + r;
    if (pp < KPN) {                     // pp==15 (g16==3,r==3) is the dummy row
      agg_s[w][pp*SCC +      p] = acc0[r];
      agg_s[w][pp*SCC + 16 + p] = acc1[r];
      agg_s[w][pp*SCC + 32 + p] = acc2[r];
      agg_s[w][pp*SCC + 48 + p] = acc3[r];
    }
  }
  // Phase B: h2 = agg @ Wkp. Wave w owns rows w*8..w*8+7 of each 64-row chunk,
  // read straight from global (L2-resident, each element read once per block).
  int jg = lane >> 4;            // 0..3
  int dq = (lane & 15) * 4;      // dim group
  int jbase = w*8 + jg*2;        // rows within chunk
  f32x4 acc4[NT];
  #pragma unroll
  for (int pt = 0; pt < NT; ++pt) acc4[pt] = (f32x4){0.f,0.f,0.f,0.f};
  float4 nx0 = *(const float4*)&Wkp[(size_t)(jbase    )*SCC + dq];
  float4 nx1 = *(const float4*)&Wkp[(size_t)(jbase + 1)*SCC + dq];
  __syncthreads();               // publish agg_s (the ONLY pre-epilogue barrier)
  for (int c0 = 0; c0 < KPN*SCC; c0 += 64) {
    float4 wv0 = nx0, wv1 = nx1;
    if (c0 + 64 < KPN*SCC) {     // depth-1 prefetch of next chunk's rows
      nx0 = *(const float4*)&Wkp[(size_t)(c0 + 64 + jbase    )*SCC + dq];
      nx1 = *(const float4*)&Wkp[(size_t)(c0 + 64 + jbase + 1)*SCC + dq];
    }
    #pragma unroll
    for (int pt = 0; pt < NT; ++pt) {
      float2 av = *(const float2*)&agg_s[pt][c0 + jbase];
      acc4[pt].x = fmaf(av.x, wv0.x, acc4[pt].x);
      acc4[pt].y = fmaf(av.x, wv0.y, acc4[pt].y);
      acc4[pt].z = fmaf(av.x, wv0.z, acc4[pt].z);
      acc4[pt].w = fmaf(av.x, wv0.w, acc4[pt].w);
      acc4[pt].x = fmaf(av.y, wv1.x, acc4[pt].x);
      acc4[pt].y = fmaf(av.y, wv1.y, acc4[pt].y);
      acc4[pt].z = fmaf(av.y, wv1.z, acc4[pt].z);
      acc4[pt].w = fmaf(av.y, wv1.w, acc4[pt].w);
    }
  }
  // reduce over jg lane-groups (bits 4,5 of lane)
  #pragma unroll
  for (int pt = 0; pt < NT; ++pt) {
    acc4[pt].x += __shfl_xor(acc4[pt].x, 16); acc4[pt].x += __shfl_xor(acc4[pt].x, 32);
    acc4[pt].y += __shfl_xor(acc4[pt].y, 16); acc4[pt].y += __shfl_xor(acc4[pt].y, 32);
    acc4[pt].z += __shfl_xor(acc4[pt].z, 16); acc4[pt].z += __shfl_xor(acc4[pt].z, 32);
    acc4[pt].w += __shfl_xor(acc4[pt].w, 16); acc4[pt].w += __shfl_xor(acc4[pt].w, 32);
  }
  __syncthreads();               // all agg_s reads done -> red_s overlay safe
  if (lane < 16) {
    #pragma unroll
    for (int pt = 0; pt < NT; ++pt) {
      float4 v; v.x = acc4[pt].x; v.y = acc4[pt].y; v.z = acc4[pt].z; v.w = acc4[pt].w;
      *(float4*)&red_s[w][pt*SCC + dq] = v;
    }
  }
  __syncthreads();               // publish red_s
  {
    int pt = t >> 6, d = t & 63; // one h2 element per thread, coalesced store
    float s = 0.f;
    #pragma unroll
    for (int w8 = 0; w8 < NT; ++w8) s += red_s[w8][pt*SCC + d];
    h2[((size_t)blockIdx.x*NT + pt)*SCC + d] = s;
  }
}

// ---- conv_out + bias + BN partial stats: tiled GEMM, all operands in LDS -----
__global__ __launch_bounds__(512) void conv_out_bn(
    const float* __restrict__ h2, const float* __restrict__ W,
    const float* __restrict__ b, float* __restrict__ y,
    float* __restrict__ stats)
{
  __shared__ float w_s[SCC*OUTC];      // 64 KB
  __shared__ float h_s[COB][SCC];      // 8 KB
  __shared__ float rs_s[2][OUTC];      // 2 KB
  __shared__ float rs2_s[2][OUTC];     // 2 KB
  int t = threadIdx.x;
  int d = t & 255, rg = t >> 8;        // rg in {0,1}: 16-row halves
  int row0 = blockIdx.x*COB;
  int cloud = (int)(blockIdx.x >> 8);  // 256 blocks per cloud
  {
    const float4* gw = (const float4*)W;
    float4* lw = (float4*)w_s;
    #pragma unroll
    for (int i = 0; i < 8; ++i) lw[t + 512*i] = gw[t + 512*i];
    const float4* gh = (const float4*)(h2 + (size_t)row0*SCC);
    ((float4*)h_s)[t] = gh[t];
  }
  __syncthreads();
  float acc[16];
  float bb = b[d];
  #pragma unroll
  for (int r = 0; r < 16; ++r) acc[r] = bb;
  int rb = rg*16;
  #pragma unroll 4
  for (int c4 = 0; c4 < 16; ++c4) {
    float w0 = w_s[(c4*4+0)*OUTC + d];
    float w1 = w_s[(c4*4+1)*OUTC + d];
    float w2 = w_s[(c4*4+2)*OUTC + d];
    float w3 = w_s[(c4*4+3)*OUTC + d];
    #pragma unroll
    for (int r = 0; r < 16; ++r) {
      float4 hv = *(const float4*)&h_s[rb + r][c4*4];
      acc[r] = fmaf(hv.x,w0, fmaf(hv.y,w1, fmaf(hv.z,w2, fmaf(hv.w,w3, acc[r]))));
    }
  }
  float s = 0.f, s2 = 0.f;
  #pragma unroll
  for (int r = 0; r < 16; ++r) {
    float v = acc[r];
    y[((size_t)row0 + rb + r)*OUTC + d] = v;
    s += v; s2 = fmaf(v, v, s2);
  }
  rs_s[rg][d] = s; rs2_s[rg][d] = s2;
  __syncthreads();
  if (rg == 0) {
    atomicAdd(&stats[cloud*512 + d],       s  + rs_s[1][d]);
    atomicAdd(&stats[cloud*512 + 256 + d], s2 + rs2_s[1][d]);
  }
}

// ---- BN apply ----------------------------------------------------------------
__global__ __launch_bounds__(256) void bn_apply_k(
    float* __restrict__ y, const float* __restrict__ stats,
    const float* __restrict__ gamma, const float* __restrict__ beta)
{
  size_t e = (size_t)blockIdx.x*256 + threadIdx.x;
  int c = (int)(e & 255);
  int cloud = (int)(e >> 21);
  float s  = stats[cloud*512 + c];
  float s2 = stats[cloud*512 + 256 + c];
  float mu  = s * (1.0f/NPTS);
  float var = fmaxf(s2 * (1.0f/NPTS) - mu*mu, 0.f);
  float sc = gamma[c] * rsqrtf(var + 1e-5f);
  float sh = beta[c] - mu*sc;
  float v = fmaf(y[e], sc, sh);
  v = v > 0.f ? v : 0.1f*v;
  y[e] = v;
}

// ---- coords tail of output (f32) + stats/hist zeroing (block 192) ------------
__global__ __launch_bounds__(256) void emit_coords(
    const float* __restrict__ scd, const float* __restrict__ tcd,
    float* __restrict__ out, float* __restrict__ stats,
    unsigned int* __restrict__ hist)
{
  int b = blockIdx.x;
  int t = threadIdx.x;
  if (b == 192) {
    for (int i = t; i < 1024; i += 256) { stats[i] = 0.f; hist[i] = 0u; }
    return;
  }
  int i = b*256 + t;    // 0..49151
  out[i] = (i < NPTS*3) ? scd[i] : tcd[i - NPTS*3];
}

extern "C" void kernel_launch(void* const* d_in, const int* in_sizes, int n_in,
                              void* d_out, int out_size, void* d_ws, size_t ws_size,
                              hipStream_t stream)
{
  (void)in_sizes; (void)n_in; (void)out_size; (void)ws_size;
  const float* src   = (const float*)d_in[0];
  const float* tgt   = (const float*)d_in[1];
  const float* scd   = (const float*)d_in[2];
  const float* tcd   = (const float*)d_in[3];
  const float* W_in  = (const float*)d_in[4];
  const float* b_in  = (const float*)d_in[5];
  const float* kpts  = (const float*)d_in[6];
  const float* W_kp  = (const float*)d_in[7];
  const float* W_out = (const float*)d_in[8];
  const float* b_out = (const float*)d_in[9];
  const float* gamma = (const float*)d_in[10];
  const float* beta  = (const float*)d_in[11];

  // ---- workspace ----
  char* ws = (char*)d_ws;
  float* h     = (float*)ws;                        // 0..4 MB  [2][8192][64]
  float* h2    = (float*)(ws + (4u<<20));           // 4..8 MB  [2][8192][64]
  short* fidx  = (short*)(ws + (8u<<20));           // 8..9 MB [16384][32] i16
  float* stats = (float*)(ws + (9u<<20));           // 4 KB
  // grid aux lives INSIDE the h2 region: dead before kpconv's first h2 write
  // (kpconv fully overwrites h2), and rebuilt from scratch every launch.
  unsigned int* hist   = (unsigned int*)(ws + (4u<<20));            // 4 KB
  unsigned int* starts = (unsigned int*)(ws + (4u<<20) + (8u<<10)); // 2x520 u32
  unsigned int* cursor = (unsigned int*)(ws + (4u<<20) + (16u<<10));// 4 KB
  float4* sorted       = (float4*)(ws + (4u<<20) + (32u<<10));      // 256 KB

  float* yout = (float*)d_out;

  emit_coords<<<193, 256, 0, stream>>>(scd, tcd, yout + (size_t)2*NPTS*OUTC,
                                       stats, hist);
  grid_count<<<64, 256, 0, stream>>>(scd, tcd, hist);
  grid_scan<<<1, 512, 0, stream>>>(hist, starts, cursor);
  grid_scatter<<<64, 256, 0, stream>>>(scd, tcd, cursor, sorted);
  knn_grid<<<4096, 256, 0, stream>>>(scd, tcd, starts, sorted, fidx);
  conv_in_k<<<1024, 256, 0, stream>>>(src, tgt, W_in, b_in, h);
  kpconv_fused<<<2048, 512, 0, stream>>>(scd, tcd, kpts, fidx, h, W_kp, h2);
  conv_out_bn<<<512, 512, 0, stream>>>(h2, W_out, b_out, yout, stats);
  bn_apply_k<<<16384, 256, 0, stream>>>(yout, stats, gamma, beta);
}

// Round 9
// 234.300 us; speedup vs baseline: 1.3186x; 1.0389x over previous
//
#include <hip/hip_runtime.h>
#include <stdint.h>

#define NPTS 8192
#define KNN 32
#define KPN 15
#define SCC 64
#define OUTC 256
#define R2F 0.0144f              /* radius^2: the reference's in_range mask.
                                    NOTE: must be RADIUS^2, NOT EXTENT^2 —
                                    influence is dist(rel, kernel_pt) < EXT,
                                    and kernel points are offset from origin,
                                    so neighbors in (EXT, RADIUS] contribute. */
#define INV_EXT (1.0f/0.096f)
#define SCAP 128                 /* per-query survivor cap */
#define NT 8                     /* points per kpconv block */
#define COB 32                   /* rows per conv_out block */
#define GD 8                     /* grid dim: cell 0.125 >= RADIUS 0.12 */
#define NCELL (GD*GD*GD)         /* 512 cells per cloud */
#define KJ (KPN*SCC)             /* 960: contraction length */
#define AGP 968                  /* agg_s row stride: 968*2B = 484 dwords,
                                    484 % 32 = 4 -> 8 pt-rows hit 8 distinct
                                    banks on ds_read_b128 (conflict-free) */

typedef float  f32x4  __attribute__((ext_vector_type(4)));
typedef __bf16 bf16x8 __attribute__((ext_vector_type(8)));

__device__ __forceinline__ int cell_of(float x) {
  int c = (int)(x * (float)GD);
  return c < 0 ? 0 : (c > GD-1 ? GD-1 : c);
}

// ---- conv_in: 4 rows per thread (lane = channel), bf16 output ---------------
__global__ __launch_bounds__(256) void conv_in_k(
    const float* __restrict__ src, const float* __restrict__ tgt,
    const float* __restrict__ W, const float* __restrict__ b,
    __bf16* __restrict__ h)
{
  int t = threadIdx.x;
  int w = t >> 6, c = t & 63;
  int row = blockIdx.x*16 + w*4;          // 0..16383 = cloud*NPTS+n (no straddle)
  const float* x = (row >> 13) ? tgt : src;
  int n0 = row & 8191;
  const float4* x0 = (const float4*)(x + (size_t)n0*256);
  const float4* x1 = x0 + 64;
  const float4* x2 = x0 + 128;
  const float4* x3 = x0 + 192;
  float bc = b[c];
  float a0 = bc, a1 = bc, a2 = bc, a3 = bc;
  #pragma unroll 4
  for (int k4 = 0; k4 < 64; ++k4) {
    float4 v0 = x0[k4], v1 = x1[k4], v2 = x2[k4], v3 = x3[k4];
    const float* wp = W + (size_t)k4*4*64 + c;
    float w0 = wp[0], w1 = wp[64], w2 = wp[128], w3 = wp[192];
    a0 = fmaf(v0.x,w0,a0); a0 = fmaf(v0.y,w1,a0); a0 = fmaf(v0.z,w2,a0); a0 = fmaf(v0.w,w3,a0);
    a1 = fmaf(v1.x,w0,a1); a1 = fmaf(v1.y,w1,a1); a1 = fmaf(v1.z,w2,a1); a1 = fmaf(v1.w,w3,a1);
    a2 = fmaf(v2.x,w0,a2); a2 = fmaf(v2.y,w1,a2); a2 = fmaf(v2.z,w2,a2); a2 = fmaf(v2.w,w3,a2);
    a3 = fmaf(v3.x,w0,a3); a3 = fmaf(v3.y,w1,a3); a3 = fmaf(v3.z,w2,a3); a3 = fmaf(v3.w,w3,a3);
  }
  __bf16* hr = h + (size_t)row*SCC + c;
  hr[0] = (__bf16)a0; hr[64] = (__bf16)a1; hr[128] = (__bf16)a2; hr[192] = (__bf16)a3;
}

// ---- W_kp transpose + bf16 cvt: WkpT[d][j] = Wkp[j][d] -----------------------
__global__ __launch_bounds__(256) void wkp_cvt(
    const float* __restrict__ Wkp, __bf16* __restrict__ WkpT)
{
  int i = blockIdx.x*256 + threadIdx.x;   // 0..61439 (240 blocks, exact)
  int j = i >> 6, d = i & 63;             // coalesced read of Wkp
  WkpT[(size_t)d*KJ + j] = (__bf16)Wkp[i];
}

// ---- spatial-grid build: count -> scan -> scatter ----------------------------
__global__ __launch_bounds__(256) void grid_count(
    const float* __restrict__ cA, const float* __restrict__ cB,
    unsigned int* __restrict__ hist)
{
  int i = blockIdx.x*256 + threadIdx.x;   // 0..16383
  int cloud = i >> 13, n = i & 8191;
  const float* coords = cloud ? cB : cA;
  int cx = cell_of(coords[(size_t)n*3]);
  int cy = cell_of(coords[(size_t)n*3+1]);
  int cz = cell_of(coords[(size_t)n*3+2]);
  atomicAdd(&hist[cloud*NCELL + (cz*GD + cy)*GD + cx], 1u);
}

__global__ __launch_bounds__(512) void grid_scan(
    const unsigned int* __restrict__ hist,
    unsigned int* __restrict__ starts,     // [2][520], [512] = total
    unsigned int* __restrict__ cursor)     // [2][512]
{
  __shared__ unsigned int a[NCELL], b[NCELL];
  int t = threadIdx.x;
  for (int cloud = 0; cloud < 2; ++cloud) {
    unsigned int v = hist[cloud*NCELL + t];
    a[t] = v; __syncthreads();
    unsigned int *src = a, *dst = b;
    for (int off = 1; off < NCELL; off <<= 1) {
      unsigned int x = src[t];
      if (t >= off) x += src[t - off];
      dst[t] = x; __syncthreads();
      unsigned int* tmp = src; src = dst; dst = tmp;
    }
    unsigned int inc = src[t];
    unsigned int exc = inc - v;
    starts[cloud*520 + t] = exc;
    cursor[cloud*NCELL + t] = exc;
    if (t == NCELL-1) starts[cloud*520 + NCELL] = inc;   // = 8192
    __syncthreads();
  }
}

__global__ __launch_bounds__(256) void grid_scatter(
    const float* __restrict__ cA, const float* __restrict__ cB,
    unsigned int* __restrict__ cursor, float4* __restrict__ sorted)
{
  int i = blockIdx.x*256 + threadIdx.x;   // 0..16383
  int cloud = i >> 13, n = i & 8191;
  const float* coords = cloud ? cB : cA;
  float x = coords[(size_t)n*3], y = coords[(size_t)n*3+1], z = coords[(size_t)n*3+2];
  int cell = (cell_of(z)*GD + cell_of(y))*GD + cell_of(x);
  unsigned int slot = atomicAdd(&cursor[cloud*NCELL + cell], 1u);
  sorted[(size_t)cloud*NPTS + slot] = make_float4(x, y, z, __int_as_float(n));
}

// ---- kNN v4: spatial grid, one wave per query --------------------------------
__global__ __launch_bounds__(256) void knn_grid(
    const float* __restrict__ cA, const float* __restrict__ cB,
    const unsigned int* __restrict__ starts, const float4* __restrict__ sorted,
    short* __restrict__ fidx)
{
  __shared__ unsigned long long surv[4][SCAP];   // 4 KB, wave-private rows
  int t = threadIdx.x, w = t >> 6, lane = t & 63;
  int q = blockIdx.x*4 + w;            // 0..16383
  int cloud = q >> 13, n = q & 8191;
  const float* coords = cloud ? cB : cA;
  float qx = coords[(size_t)n*3];
  float qy = coords[(size_t)n*3+1];
  float qz = coords[(size_t)n*3+2];
  int cx = cell_of(qx), cy = cell_of(qy), cz = cell_of(qz);
  const unsigned int* st = starts + cloud*520;
  const float4* sp = sorted + (size_t)cloud*NPTS;
  int c0 = cx > 0 ? cx-1 : 0;
  int c1 = cx < GD-1 ? cx+1 : GD-1;
  unsigned int cnt = 0;
  for (int dz = -1; dz <= 1; ++dz) {
    int zz = cz + dz; if (zz < 0 || zz > GD-1) continue;
    for (int dy = -1; dy <= 1; ++dy) {
      int yy = cy + dy; if (yy < 0 || yy > GD-1) continue;
      int rb = (zz*GD + yy)*GD;
      unsigned int s = st[rb + c0];
      unsigned int e = st[rb + c1 + 1];
      for (unsigned int jj = s; jj < e; jj += 64) {
        unsigned int j = jj + lane;
        bool keep = false; float d2 = 0.f; unsigned int oi = 0;
        if (j < e) {
          float4 p = sp[j];
          float dx = qx-p.x, dyy = qy-p.y, dzz = qz-p.z;
          d2 = fmaf(dx, dx, fmaf(dyy, dyy, dzz*dzz));
          oi = __float_as_uint(p.w);
          keep = (d2 <= R2F);
        }
        unsigned long long m = __ballot(keep);
        if (keep) {
          unsigned int before = __builtin_amdgcn_mbcnt_hi(
              (unsigned int)(m >> 32),
              __builtin_amdgcn_mbcnt_lo((unsigned int)m, 0u));
          unsigned int pos = cnt + before;
          if (pos < SCAP)
            surv[w][pos] = ((unsigned long long)__float_as_uint(d2) << 32) | oi;
        }
        cnt += (unsigned int)__popcll(m);
      }
    }
  }
  int C = (int)cnt; if (C > SCAP) C = SCAP;
  unsigned long long k0 = (lane      < C) ? surv[w][lane]      : ~0ULL;
  unsigned long long k1 = (lane + 64 < C) ? surv[w][lane + 64] : ~0ULL;
  int r0 = 0, r1 = 0;
  for (int j = 0; j < C; ++j) {
    unsigned long long kj = surv[w][j];      // same addr all lanes: broadcast
    r0 += (kj < k0);
    r1 += (kj < k1);
  }
  size_t g = (size_t)cloud*NPTS + n;
  if (k0 != ~0ULL && r0 < KNN) fidx[g*KNN + r0] = (short)(k0 & 0xffffu);
  if (k1 != ~0ULL && r1 < KNN) fidx[g*KNN + r1] = (short)(k1 & 0xffffu);
  if (lane >= C && lane < KNN) fidx[g*KNN + lane] = (short)-1;   // sentinels
}

// ---- fused KPConv v5: MFMA Phase A AND Phase B, 8 points/block ---------------
// Phase A (per wave = point): agg(15x64) = w(15x32) @ h(32x64), 4 MFMA,
//   D stored to agg_s as bf16 (row pt=w, j = pp*64+c, padded stride AGP).
// Phase B: D[d][pt] = sum_j WkpT[d][j]*agg[pt][j]. 8 waves = 4 d-tiles x
//   2 K-halves; per wave 15 x mfma_16x16x32_bf16. A-frag = 16B load from
//   pre-transposed WkpT (L2-hot); B-frag = 1 conflict-free ds_read_b128.
//   K-order cancels between A and B (same slot mapping); C/D layout is the
//   HW-verified col=lane&15, row=(lane>>4)*4+reg.
// 2 barriers total; LDS 23.7 KB.
__global__ __launch_bounds__(512) void kpconv_fused(
    const float* __restrict__ cA, const float* __restrict__ cB,
    const float* __restrict__ kpts, const short* __restrict__ fidx,
    const __bf16* __restrict__ h, const __bf16* __restrict__ WkpT,
    float* __restrict__ h2)
{
  __shared__ __bf16 agg_s[NT][AGP];     // 15.5 KB
  __shared__ float  red_s[NT][256];     // 8 KB
  int t = threadIdx.x;
  int w = t >> 6, lane = t & 63;
  int gq = blockIdx.x*NT + w;           // 0..16383 = cloud*NPTS + n
  int cloud = gq >> 13, n = gq & 8191;
  const float* coords = cloud ? cB : cA;
  int idxreg = fidx[(size_t)gq*KNN + (lane & 31)];   // lanes 32-63 mirror 0-31
  float qx = coords[(size_t)n*3];
  float qy = coords[(size_t)n*3+1];
  float qz = coords[(size_t)n*3+2];
  int g16 = lane >> 4;                  // k-group: this lane covers k=g16*8+j
  int p   = lane & 15;                  // A-row (kernel point) and B/D column
  int pc  = p < KPN ? p : 0;            // clamp: p==15 row is zero-weighted
  float kpx = kpts[pc*3], kpy = kpts[pc*3+1], kpz = kpts[pc*3+2];
  // A-fragment: w[p][k] in bf16; remember clamped idx per j for the gather.
  bf16x8 afrag;
  int idxs[8];
  #pragma unroll
  for (int j = 0; j < 8; ++j) {
    int k = g16*8 + j;
    int idx = __shfl(idxreg, k);        // idx for neighbor k (lanes 0-31 hold)
    idxs[j] = idx < 0 ? 0 : idx;
    float wv = 0.f;
    if (idx >= 0 && p < KPN) {
      float rx = coords[(size_t)idx*3]   - qx;
      float ry = coords[(size_t)idx*3+1] - qy;
      float rz = coords[(size_t)idx*3+2] - qz;
      float dx = rx - kpx, dy = ry - kpy, dz = rz - kpz;
      float d = sqrtf(fmaf(dx, dx, fmaf(dy, dy, dz*dz)));
      wv = fmaxf(1.0f - d*INV_EXT, 0.0f);
    }
    afrag[j] = (__bf16)wv;              // idx<0 -> 0: zero A kills garbage B
  }
  // B-fragments: h[idx_k][ct*16 + p] (bf16, no cvt), 4 channel tiles.
  bf16x8 bfrag0, bfrag1, bfrag2, bfrag3;
  #pragma unroll
  for (int j = 0; j < 8; ++j) {
    const __bf16* hrow = h + ((size_t)(cloud*NPTS + idxs[j]))*SCC + p;
    bfrag0[j] = hrow[0];
    bfrag1[j] = hrow[16];
    bfrag2[j] = hrow[32];
    bfrag3[j] = hrow[48];
  }
  f32x4 acc0 = {0.f,0.f,0.f,0.f}, acc1 = acc0, acc2 = acc0, acc3 = acc0;
  acc0 = __builtin_amdgcn_mfma_f32_16x16x32_bf16(afrag, bfrag0, acc0, 0, 0, 0);
  acc1 = __builtin_amdgcn_mfma_f32_16x16x32_bf16(afrag, bfrag1, acc1, 0, 0, 0);
  acc2 = __builtin_amdgcn_mfma_f32_16x16x32_bf16(afrag, bfrag2, acc2, 0, 0, 0);
  acc3 = __builtin_amdgcn_mfma_f32_16x16x32_bf16(afrag, bfrag3, acc3, 0, 0, 0);
  // Store D -> agg_s bf16: row pp=g16*4+r, cols ct*16+p.
  #pragma unroll
  for (int r = 0; r < 4; ++r) {
    int pp = g16*4 + r;
    if (pp < KPN) {                     // pp==15 is the dummy row
      agg_s[w][pp*SCC +      p] = (__bf16)acc0[r];
      agg_s[w][pp*SCC + 16 + p] = (__bf16)acc1[r];
      agg_s[w][pp*SCC + 32 + p] = (__bf16)acc2[r];
      agg_s[w][pp*SCC + 48 + p] = (__bf16)acc3[r];
    }
  }
  __syncthreads();                      // publish agg_s
  // Phase B: wave = (d-tile dt, K-half kh). 15 MFMA, K=480 each half.
  {
    int dt = w & 3, kh = w >> 2;
    int ptb = p & 7;                    // B col -> point (cols 8-15 unused)
    const __bf16* arow = WkpT + (size_t)(dt*16 + p)*KJ + kh*480 + g16*8;
    const __bf16* brow = &agg_s[ptb][kh*480 + g16*8];
    f32x4 accB = {0.f,0.f,0.f,0.f};
    #pragma unroll
    for (int s = 0; s < 15; ++s) {
      bf16x8 af = *(const bf16x8*)(arow + s*32);
      bf16x8 bf = *(const bf16x8*)(brow + s*32);
      accB = __builtin_amdgcn_mfma_f32_16x16x32_bf16(af, bf, accB, 0, 0, 0);
    }
    *(float4*)&red_s[w][lane*4] = *(float4*)&accB;   // wave-private row
  }
  __syncthreads();                      // publish red_s
  {
    int pt = t >> 6, d = t & 63;        // one h2 element, coalesced store
    int dt2 = d >> 4, m2 = d & 15;      // D row m=d-in-tile -> lane/reg
    int l = (m2 >> 2)*16 + pt;
    int r = m2 & 3;
    float v = red_s[dt2][l*4 + r] + red_s[4 + dt2][l*4 + r];
    h2[((size_t)blockIdx.x*NT + pt)*SCC + d] = v;
  }
}

// ---- conv_out + bias + BN partial stats: tiled GEMM, all operands in LDS -----
__global__ __launch_bounds__(512) void conv_out_bn(
    const float* __restrict__ h2, const float* __restrict__ W,
    const float* __restrict__ b, float* __restrict__ y,
    float* __restrict__ stats)
{
  __shared__ float w_s[SCC*OUTC];      // 64 KB
  __shared__ float h_s[COB][SCC];      // 8 KB
  __shared__ float rs_s[2][OUTC];      // 2 KB
  __shared__ float rs2_s[2][OUTC];     // 2 KB
  int t = threadIdx.x;
  int d = t & 255, rg = t >> 8;        // rg in {0,1}: 16-row halves
  int row0 = blockIdx.x*COB;
  int cloud = (int)(blockIdx.x >> 8);  // 256 blocks per cloud
  {
    const float4* gw = (const float4*)W;
    float4* lw = (float4*)w_s;
    #pragma unroll
    for (int i = 0; i < 8; ++i) lw[t + 512*i] = gw[t + 512*i];
    const float4* gh = (const float4*)(h2 + (size_t)row0*SCC);
    ((float4*)h_s)[t] = gh[t];
  }
  __syncthreads();
  float acc[16];
  float bb = b[d];
  #pragma unroll
  for (int r = 0; r < 16; ++r) acc[r] = bb;
  int rb = rg*16;
  #pragma unroll 4
  for (int c4 = 0; c4 < 16; ++c4) {
    float w0 = w_s[(c4*4+0)*OUTC + d];
    float w1 = w_s[(c4*4+1)*OUTC + d];
    float w2 = w_s[(c4*4+2)*OUTC + d];
    float w3 = w_s[(c4*4+3)*OUTC + d];
    #pragma unroll
    for (int r = 0; r < 16; ++r) {
      float4 hv = *(const float4*)&h_s[rb + r][c4*4];
      acc[r] = fmaf(hv.x,w0, fmaf(hv.y,w1, fmaf(hv.z,w2, fmaf(hv.w,w3, acc[r]))));
    }
  }
  float s = 0.f, s2 = 0.f;
  #pragma unroll
  for (int r = 0; r < 16; ++r) {
    float v = acc[r];
    y[((size_t)row0 + rb + r)*OUTC + d] = v;
    s += v; s2 = fmaf(v, v, s2);
  }
  rs_s[rg][d] = s; rs2_s[rg][d] = s2;
  __syncthreads();
  if (rg == 0) {
    atomicAdd(&stats[cloud*512 + d],       s  + rs_s[1][d]);
    atomicAdd(&stats[cloud*512 + 256 + d], s2 + rs2_s[1][d]);
  }
}

// ---- BN apply ----------------------------------------------------------------
__global__ __launch_bounds__(256) void bn_apply_k(
    float* __restrict__ y, const float* __restrict__ stats,
    const float* __restrict__ gamma, const float* __restrict__ beta)
{
  size_t e = (size_t)blockIdx.x*256 + threadIdx.x;
  int c = (int)(e & 255);
  int cloud = (int)(e >> 21);
  float s  = stats[cloud*512 + c];
  float s2 = stats[cloud*512 + 256 + c];
  float mu  = s * (1.0f/NPTS);
  float var = fmaxf(s2 * (1.0f/NPTS) - mu*mu, 0.f);
  float sc = gamma[c] * rsqrtf(var + 1e-5f);
  float sh = beta[c] - mu*sc;
  float v = fmaf(y[e], sc, sh);
  v = v > 0.f ? v : 0.1f*v;
  y[e] = v;
}

// ---- coords tail of output (f32) + stats/hist zeroing (block 192) ------------
__global__ __launch_bounds__(256) void emit_coords(
    const float* __restrict__ scd, const float* __restrict__ tcd,
    float* __restrict__ out, float* __restrict__ stats,
    unsigned int* __restrict__ hist)
{
  int b = blockIdx.x;
  int t = threadIdx.x;
  if (b == 192) {
    for (int i = t; i < 1024; i += 256) { stats[i] = 0.f; hist[i] = 0u; }
    return;
  }
  int i = b*256 + t;    // 0..49151
  out[i] = (i < NPTS*3) ? scd[i] : tcd[i - NPTS*3];
}

extern "C" void kernel_launch(void* const* d_in, const int* in_sizes, int n_in,
                              void* d_out, int out_size, void* d_ws, size_t ws_size,
                              hipStream_t stream)
{
  (void)in_sizes; (void)n_in; (void)out_size; (void)ws_size;
  const float* src   = (const float*)d_in[0];
  const float* tgt   = (const float*)d_in[1];
  const float* scd   = (const float*)d_in[2];
  const float* tcd   = (const float*)d_in[3];
  const float* W_in  = (const float*)d_in[4];
  const float* b_in  = (const float*)d_in[5];
  const float* kpts  = (const float*)d_in[6];
  const float* W_kp  = (const float*)d_in[7];
  const float* W_out = (const float*)d_in[8];
  const float* b_out = (const float*)d_in[9];
  const float* gamma = (const float*)d_in[10];
  const float* beta  = (const float*)d_in[11];

  // ---- workspace ----
  char* ws = (char*)d_ws;
  __bf16* h    = (__bf16*)ws;                       // 0..2 MB  [2][8192][64] bf16
  float* h2    = (float*)(ws + (4u<<20));           // 4..8 MB  [2][8192][64] f32
  short* fidx  = (short*)(ws + (8u<<20));           // 8..9 MB [16384][32] i16
  float* stats = (float*)(ws + (9u<<20));           // 4 KB
  __bf16* WkpT = (__bf16*)(ws + (9u<<20) + (64u<<10)); // 120 KB [64][960] bf16
  // grid aux lives INSIDE the h2 region: dead before kpconv's first h2 write
  unsigned int* hist   = (unsigned int*)(ws + (4u<<20));            // 4 KB
  unsigned int* starts = (unsigned int*)(ws + (4u<<20) + (8u<<10)); // 2x520 u32
  unsigned int* cursor = (unsigned int*)(ws + (4u<<20) + (16u<<10));// 4 KB
  float4* sorted       = (float4*)(ws + (4u<<20) + (32u<<10));      // 256 KB

  float* yout = (float*)d_out;

  emit_coords<<<193, 256, 0, stream>>>(scd, tcd, yout + (size_t)2*NPTS*OUTC,
                                       stats, hist);
  wkp_cvt<<<240, 256, 0, stream>>>(W_kp, WkpT);
  grid_count<<<64, 256, 0, stream>>>(scd, tcd, hist);
  grid_scan<<<1, 512, 0, stream>>>(hist, starts, cursor);
  grid_scatter<<<64, 256, 0, stream>>>(scd, tcd, cursor, sorted);
  knn_grid<<<4096, 256, 0, stream>>>(scd, tcd, starts, sorted, fidx);
  conv_in_k<<<1024, 256, 0, stream>>>(src, tgt, W_in, b_in, h);
  kpconv_fused<<<2048, 512, 0, stream>>>(scd, tcd, kpts, fidx, h, WkpT, h2);
  conv_out_bn<<<512, 512, 0, stream>>>(h2, W_out, b_out, yout, stats);
  bn_apply_k<<<16384, 256, 0, stream>>>(yout, stats, gamma, beta);
}

// Round 10
// 197.997 us; speedup vs baseline: 1.5604x; 1.1834x over previous
//
#include <hip/hip_runtime.h>
#include <stdint.h>

#define NPTS 8192
#define KNN 32
#define KPN 15
#define SCC 64
#define OUTC 256
#define R2F 0.0144f              /* radius^2: the reference's in_range mask.
                                    NOTE: must be RADIUS^2, NOT EXTENT^2 —
                                    influence is dist(rel, kernel_pt) < EXT,
                                    and kernel points are offset from origin,
                                    so neighbors in (EXT, RADIUS] contribute. */
#define INV_EXT (1.0f/0.096f)
#define SCAP 128                 /* per-query survivor cap */
#define NT 8                     /* points per kpconv block */
#define COB 32                   /* rows per conv_out block */
#define GD 8                     /* grid dim: cell 0.125 >= RADIUS 0.12 */
#define NCELL (GD*GD*GD)         /* 512 cells per cloud */
#define KJ (KPN*SCC)             /* 960: contraction length */
#define AGP 968                  /* agg_s row stride (bf16): bank-spread-ish */

typedef float  f32x4  __attribute__((ext_vector_type(4)));
typedef __bf16 bf16x8 __attribute__((ext_vector_type(8)));

__device__ __forceinline__ int cell_of(float x) {
  int c = (int)(x * (float)GD);
  return c < 0 ? 0 : (c > GD-1 ? GD-1 : c);
}

// ---- W_in -> fragment-ordered bf16: WinF[(kc*4+ct)*512 + lane*8 + j] --------
// = W_in[(kc*32 + (lane>>4)*8 + j)*64 + ct*16 + (lane&15)]  (32 KB, L2-hot)
__global__ __launch_bounds__(256) void win_cvt(
    const float* __restrict__ W, __bf16* __restrict__ WinF)
{
  int i = blockIdx.x*256 + threadIdx.x;   // 0..16383
  int j = i & 7, lane = (i >> 3) & 63, cc = i >> 9;  // cc = kc*4+ct
  int kc = cc >> 2, ct = cc & 3;
  int g16 = lane >> 4, p = lane & 15;
  int k = kc*32 + g16*8 + j;
  WinF[i] = (__bf16)W[(size_t)k*64 + ct*16 + p];
}

// ---- conv_in v2: MFMA GEMM [16384x256]@[256x64], 16 rows/wave ---------------
// Fragment contract (HW-verified in kpconv rounds 8/9): afrag = A[m=lane&15]
// [kslot(g16,j)], bfrag = B[kslot][n=lane&15], D col=lane&15 row=(lane>>4)*4+r.
// A loads: lane reads x[row0+p][kc*32+g16*8..+7] -> per k-chunk the wave reads
// 16 rows x 128B contiguous (each x element exactly once, coalesced, 16
// independent HBM loads deep). B: one 16B L2 load per MFMA. Bias in C-init.
__global__ __launch_bounds__(128) void conv_in_mfma(
    const float* __restrict__ src, const float* __restrict__ tgt,
    const __bf16* __restrict__ WinF, const float* __restrict__ b,
    __bf16* __restrict__ h)
{
  int t = threadIdx.x;
  int w = t >> 6, lane = t & 63;
  int rt = blockIdx.x*2 + w;           // row-tile 0..1023 (16 rows each)
  int row0 = rt*16;                    // cloud*8192 + n0 (no straddle)
  const float* x = (row0 >> 13) ? tgt : src;
  int n0 = row0 & 8191;
  int g16 = lane >> 4, p = lane & 15;
  const float* xrow = x + (size_t)(n0 + p)*256;    // this lane's A-row
  f32x4 acc[4];
  #pragma unroll
  for (int ct = 0; ct < 4; ++ct) {
    float bb = b[ct*16 + p];           // bias per D-column (col = ct*16+p)
    acc[ct] = (f32x4){bb, bb, bb, bb};
  }
  #pragma unroll
  for (int kc = 0; kc < 8; ++kc) {
    float4 xa = *(const float4*)(xrow + kc*32 + g16*8);
    float4 xb = *(const float4*)(xrow + kc*32 + g16*8 + 4);
    bf16x8 af;
    af[0]=(__bf16)xa.x; af[1]=(__bf16)xa.y; af[2]=(__bf16)xa.z; af[3]=(__bf16)xa.w;
    af[4]=(__bf16)xb.x; af[5]=(__bf16)xb.y; af[6]=(__bf16)xb.z; af[7]=(__bf16)xb.w;
    #pragma unroll
    for (int ct = 0; ct < 4; ++ct) {
      bf16x8 bf = *(const bf16x8*)(WinF + (size_t)(kc*4 + ct)*512 + lane*8);
      acc[ct] = __builtin_amdgcn_mfma_f32_16x16x32_bf16(af, bf, acc[ct], 0,0,0);
    }
  }
  // D: local row m = g16*4+r, col = ct*16+p
  #pragma unroll
  for (int ct = 0; ct < 4; ++ct)
    #pragma unroll
    for (int r = 0; r < 4; ++r)
      h[(size_t)(row0 + g16*4 + r)*SCC + ct*16 + p] = (__bf16)acc[ct][r];
}

// ---- spatial-grid build: count -> scan -> scatter ----------------------------
__global__ __launch_bounds__(256) void grid_count(
    const float* __restrict__ cA, const float* __restrict__ cB,
    unsigned int* __restrict__ hist)
{
  int i = blockIdx.x*256 + threadIdx.x;   // 0..16383
  int cloud = i >> 13, n = i & 8191;
  const float* coords = cloud ? cB : cA;
  int cx = cell_of(coords[(size_t)n*3]);
  int cy = cell_of(coords[(size_t)n*3+1]);
  int cz = cell_of(coords[(size_t)n*3+2]);
  atomicAdd(&hist[cloud*NCELL + (cz*GD + cy)*GD + cx], 1u);
}

__global__ __launch_bounds__(512) void grid_scan(
    const unsigned int* __restrict__ hist,
    unsigned int* __restrict__ starts,     // [2][520], [512] = total
    unsigned int* __restrict__ cursor)     // [2][512]
{
  __shared__ unsigned int a[NCELL], b[NCELL];
  int t = threadIdx.x;
  for (int cloud = 0; cloud < 2; ++cloud) {
    unsigned int v = hist[cloud*NCELL + t];
    a[t] = v; __syncthreads();
    unsigned int *src = a, *dst = b;
    for (int off = 1; off < NCELL; off <<= 1) {
      unsigned int x = src[t];
      if (t >= off) x += src[t - off];
      dst[t] = x; __syncthreads();
      unsigned int* tmp = src; src = dst; dst = tmp;
    }
    unsigned int inc = src[t];
    unsigned int exc = inc - v;
    starts[cloud*520 + t] = exc;
    cursor[cloud*NCELL + t] = exc;
    if (t == NCELL-1) starts[cloud*520 + NCELL] = inc;   // = 8192
    __syncthreads();
  }
}

__global__ __launch_bounds__(256) void grid_scatter(
    const float* __restrict__ cA, const float* __restrict__ cB,
    unsigned int* __restrict__ cursor, float4* __restrict__ sorted)
{
  int i = blockIdx.x*256 + threadIdx.x;   // 0..16383
  int cloud = i >> 13, n = i & 8191;
  const float* coords = cloud ? cB : cA;
  float x = coords[(size_t)n*3], y = coords[(size_t)n*3+1], z = coords[(size_t)n*3+2];
  int cell = (cell_of(z)*GD + cell_of(y))*GD + cell_of(x);
  unsigned int slot = atomicAdd(&cursor[cloud*NCELL + cell], 1u);
  sorted[(size_t)cloud*NPTS + slot] = make_float4(x, y, z, __int_as_float(n));
}

// ---- kNN v4: spatial grid, one wave per query --------------------------------
__global__ __launch_bounds__(256) void knn_grid(
    const float* __restrict__ cA, const float* __restrict__ cB,
    const unsigned int* __restrict__ starts, const float4* __restrict__ sorted,
    short* __restrict__ fidx)
{
  __shared__ unsigned long long surv[4][SCAP];   // 4 KB, wave-private rows
  int t = threadIdx.x, w = t >> 6, lane = t & 63;
  int q = blockIdx.x*4 + w;            // 0..16383
  int cloud = q >> 13, n = q & 8191;
  const float* coords = cloud ? cB : cA;
  float qx = coords[(size_t)n*3];
  float qy = coords[(size_t)n*3+1];
  float qz = coords[(size_t)n*3+2];
  int cx = cell_of(qx), cy = cell_of(qy), cz = cell_of(qz);
  const unsigned int* st = starts + cloud*520;
  const float4* sp = sorted + (size_t)cloud*NPTS;
  int c0 = cx > 0 ? cx-1 : 0;
  int c1 = cx < GD-1 ? cx+1 : GD-1;
  unsigned int cnt = 0;
  for (int dz = -1; dz <= 1; ++dz) {
    int zz = cz + dz; if (zz < 0 || zz > GD-1) continue;
    for (int dy = -1; dy <= 1; ++dy) {
      int yy = cy + dy; if (yy < 0 || yy > GD-1) continue;
      int rb = (zz*GD + yy)*GD;
      unsigned int s = st[rb + c0];
      unsigned int e = st[rb + c1 + 1];
      for (unsigned int jj = s; jj < e; jj += 64) {
        unsigned int j = jj + lane;
        bool keep = false; float d2 = 0.f; unsigned int oi = 0;
        if (j < e) {
          float4 p = sp[j];
          float dx = qx-p.x, dyy = qy-p.y, dzz = qz-p.z;
          d2 = fmaf(dx, dx, fmaf(dyy, dyy, dzz*dzz));
          oi = __float_as_uint(p.w);
          keep = (d2 <= R2F);
        }
        unsigned long long m = __ballot(keep);
        if (keep) {
          unsigned int before = __builtin_amdgcn_mbcnt_hi(
              (unsigned int)(m >> 32),
              __builtin_amdgcn_mbcnt_lo((unsigned int)m, 0u));
          unsigned int pos = cnt + before;
          if (pos < SCAP)
            surv[w][pos] = ((unsigned long long)__float_as_uint(d2) << 32) | oi;
        }
        cnt += (unsigned int)__popcll(m);
      }
    }
  }
  int C = (int)cnt; if (C > SCAP) C = SCAP;
  unsigned long long k0 = (lane      < C) ? surv[w][lane]      : ~0ULL;
  unsigned long long k1 = (lane + 64 < C) ? surv[w][lane + 64] : ~0ULL;
  int r0 = 0, r1 = 0;
  for (int j = 0; j < C; ++j) {
    unsigned long long kj = surv[w][j];      // same addr all lanes: broadcast
    r0 += (kj < k0);
    r1 += (kj < k1);
  }
  size_t g = (size_t)cloud*NPTS + n;
  if (k0 != ~0ULL && r0 < KNN) fidx[g*KNN + r0] = (short)(k0 & 0xffffu);
  if (k1 != ~0ULL && r1 < KNN) fidx[g*KNN + r1] = (short)(k1 & 0xffffu);
  if (lane >= C && lane < KNN) fidx[g*KNN + lane] = (short)-1;   // sentinels
}

// ---- fused KPConv v6: MFMA Phase A + B, conflict-free reduction layout -------
// Phase A (per wave = point): agg(15x64) = w(15x32) @ h(32x64), 4 MFMA,
//   D stored to agg_s as bf16. Phase B: D[d][pt] via 8 waves = 4 d-tiles x
//   2 K-halves, 15 MFMA each; A = pre-transposed WkpT (L2), B = agg_s b128.
// red2[kh][dt][m][pt] with 17-stride: store 2-way free, epilogue read
// d*17+pt (17 odd -> bijective banks, conflict-free; old layout was 16-way
// on banks 0-3). 2 barriers; LDS ~24 KB.
__global__ __launch_bounds__(512) void kpconv_fused(
    const float* __restrict__ cA, const float* __restrict__ cB,
    const float* __restrict__ kpts, const short* __restrict__ fidx,
    const __bf16* __restrict__ h, const __bf16* __restrict__ WkpT,
    float* __restrict__ h2)
{
  __shared__ __bf16 agg_s[NT][AGP];     // 15.5 KB
  __shared__ float  red2[2*4*16*17];    // 8.5 KB: [kh][dt][m][pt(17)]
  int t = threadIdx.x;
  int w = t >> 6, lane = t & 63;
  int gq = blockIdx.x*NT + w;           // 0..16383 = cloud*NPTS + n
  int cloud = gq >> 13, n = gq & 8191;
  const float* coords = cloud ? cB : cA;
  int idxreg = fidx[(size_t)gq*KNN + (lane & 31)];   // lanes 32-63 mirror 0-31
  float qx = coords[(size_t)n*3];
  float qy = coords[(size_t)n*3+1];
  float qz = coords[(size_t)n*3+2];
  int g16 = lane >> 4;                  // k-group: this lane covers k=g16*8+j
  int p   = lane & 15;                  // A-row (kernel point) and B/D column
  int pc  = p < KPN ? p : 0;            // clamp: p==15 row is zero-weighted
  float kpx = kpts[pc*3], kpy = kpts[pc*3+1], kpz = kpts[pc*3+2];
  // A-fragment: w[p][k] in bf16; remember clamped idx per j for the gather.
  bf16x8 afrag;
  int idxs[8];
  #pragma unroll
  for (int j = 0; j < 8; ++j) {
    int k = g16*8 + j;
    int idx = __shfl(idxreg, k);        // idx for neighbor k (lanes 0-31 hold)
    idxs[j] = idx < 0 ? 0 : idx;
    float wv = 0.f;
    if (idx >= 0 && p < KPN) {
      float rx = coords[(size_t)idx*3]   - qx;
      float ry = coords[(size_t)idx*3+1] - qy;
      float rz = coords[(size_t)idx*3+2] - qz;
      float dx = rx - kpx, dy = ry - kpy, dz = rz - kpz;
      float d = sqrtf(fmaf(dx, dx, fmaf(dy, dy, dz*dz)));
      wv = fmaxf(1.0f - d*INV_EXT, 0.0f);
    }
    afrag[j] = (__bf16)wv;              // idx<0 -> 0: zero A kills garbage B
  }
  // B-fragments: h[idx_k][ct*16 + p] (bf16, no cvt), 4 channel tiles.
  bf16x8 bfrag0, bfrag1, bfrag2, bfrag3;
  #pragma unroll
  for (int j = 0; j < 8; ++j) {
    const __bf16* hrow = h + ((size_t)(cloud*NPTS + idxs[j]))*SCC + p;
    bfrag0[j] = hrow[0];
    bfrag1[j] = hrow[16];
    bfrag2[j] = hrow[32];
    bfrag3[j] = hrow[48];
  }
  f32x4 acc0 = {0.f,0.f,0.f,0.f}, acc1 = acc0, acc2 = acc0, acc3 = acc0;
  acc0 = __builtin_amdgcn_mfma_f32_16x16x32_bf16(afrag, bfrag0, acc0, 0, 0, 0);
  acc1 = __builtin_amdgcn_mfma_f32_16x16x32_bf16(afrag, bfrag1, acc1, 0, 0, 0);
  acc2 = __builtin_amdgcn_mfma_f32_16x16x32_bf16(afrag, bfrag2, acc2, 0, 0, 0);
  acc3 = __builtin_amdgcn_mfma_f32_16x16x32_bf16(afrag, bfrag3, acc3, 0, 0, 0);
  // Store D -> agg_s bf16: row pp=g16*4+r, cols ct*16+p.
  #pragma unroll
  for (int r = 0; r < 4; ++r) {
    int pp = g16*4 + r;
    if (pp < KPN) {                     // pp==15 is the dummy row
      agg_s[w][pp*SCC +      p] = (__bf16)acc0[r];
      agg_s[w][pp*SCC + 16 + p] = (__bf16)acc1[r];
      agg_s[w][pp*SCC + 32 + p] = (__bf16)acc2[r];
      agg_s[w][pp*SCC + 48 + p] = (__bf16)acc3[r];
    }
  }
  __syncthreads();                      // publish agg_s
  // Phase B: wave = (d-tile dt, K-half kh). 15 MFMA, K=480 each half.
  {
    int dt = w & 3, kh = w >> 2;
    int ptb = p & 7;                    // B col -> point (cols 8-15 duplicate)
    const __bf16* arow = WkpT + (size_t)(dt*16 + p)*KJ + kh*480 + g16*8;
    const __bf16* brow = &agg_s[ptb][kh*480 + g16*8];
    f32x4 accB = {0.f,0.f,0.f,0.f};
    #pragma unroll
    for (int s = 0; s < 15; ++s) {
      bf16x8 af = *(const bf16x8*)(arow + s*32);
      bf16x8 bf = *(const bf16x8*)(brow + s*32);
      accB = __builtin_amdgcn_mfma_f32_16x16x32_bf16(af, bf, accB, 0, 0, 0);
    }
    if (p < 8) {                        // cols 8-15 are duplicates: drop
      #pragma unroll
      for (int r = 0; r < 4; ++r)
        red2[((kh*4 + dt)*16 + g16*4 + r)*17 + p] = accB[r];
    }
  }
  __syncthreads();                      // publish red2
  {
    int pt = t >> 6, d = t & 63;        // one h2 element, coalesced store
    // v = sum over kh of red2[kh][d>>4][d&15][pt]; addr = d*17 + pt (+kh)
    float v = red2[d*17 + pt] + red2[(64 + d)*17 + pt];
    h2[((size_t)blockIdx.x*NT + pt)*SCC + d] = v;
  }
}

// ---- conv_out + bias + BN partial stats: tiled GEMM, all operands in LDS -----
__global__ __launch_bounds__(512) void conv_out_bn(
    const float* __restrict__ h2, const float* __restrict__ W,
    const float* __restrict__ b, float* __restrict__ y,
    float* __restrict__ stats)
{
  __shared__ float w_s[SCC*OUTC];      // 64 KB
  __shared__ float h_s[COB][SCC];      // 8 KB
  __shared__ float rs_s[2][OUTC];      // 2 KB
  __shared__ float rs2_s[2][OUTC];     // 2 KB
  int t = threadIdx.x;
  int d = t & 255, rg = t >> 8;        // rg in {0,1}: 16-row halves
  int row0 = blockIdx.x*COB;
  int cloud = (int)(blockIdx.x >> 8);  // 256 blocks per cloud
  {
    const float4* gw = (const float4*)W;
    float4* lw = (float4*)w_s;
    #pragma unroll
    for (int i = 0; i < 8; ++i) lw[t + 512*i] = gw[t + 512*i];
    const float4* gh = (const float4*)(h2 + (size_t)row0*SCC);
    ((float4*)h_s)[t] = gh[t];
  }
  __syncthreads();
  float acc[16];
  float bb = b[d];
  #pragma unroll
  for (int r = 0; r < 16; ++r) acc[r] = bb;
  int rb = rg*16;
  #pragma unroll 4
  for (int c4 = 0; c4 < 16; ++c4) {
    float w0 = w_s[(c4*4+0)*OUTC + d];
    float w1 = w_s[(c4*4+1)*OUTC + d];
    float w2 = w_s[(c4*4+2)*OUTC + d];
    float w3 = w_s[(c4*4+3)*OUTC + d];
    #pragma unroll
    for (int r = 0; r < 16; ++r) {
      float4 hv = *(const float4*)&h_s[rb + r][c4*4];
      acc[r] = fmaf(hv.x,w0, fmaf(hv.y,w1, fmaf(hv.z,w2, fmaf(hv.w,w3, acc[r]))));
    }
  }
  float s = 0.f, s2 = 0.f;
  #pragma unroll
  for (int r = 0; r < 16; ++r) {
    float v = acc[r];
    y[((size_t)row0 + rb + r)*OUTC + d] = v;
    s += v; s2 = fmaf(v, v, s2);
  }
  rs_s[rg][d] = s; rs2_s[rg][d] = s2;
  __syncthreads();
  if (rg == 0) {
    atomicAdd(&stats[cloud*512 + d],       s  + rs_s[1][d]);
    atomicAdd(&stats[cloud*512 + 256 + d], s2 + rs2_s[1][d]);
  }
}

// ---- BN apply ----------------------------------------------------------------
__global__ __launch_bounds__(256) void bn_apply_k(
    float* __restrict__ y, const float* __restrict__ stats,
    const float* __restrict__ gamma, const float* __restrict__ beta)
{
  size_t e = (size_t)blockIdx.x*256 + threadIdx.x;
  int c = (int)(e & 255);
  int cloud = (int)(e >> 21);
  float s  = stats[cloud*512 + c];
  float s2 = stats[cloud*512 + 256 + c];
  float mu  = s * (1.0f/NPTS);
  float var = fmaxf(s2 * (1.0f/NPTS) - mu*mu, 0.f);
  float sc = gamma[c] * rsqrtf(var + 1e-5f);
  float sh = beta[c] - mu*sc;
  float v = fmaf(y[e], sc, sh);
  v = v > 0.f ? v : 0.1f*v;
  y[e] = v;
}

// ---- W_kp transpose + bf16 cvt: WkpT[d][j] = Wkp[j][d] -----------------------
__global__ __launch_bounds__(256) void wkp_cvt(
    const float* __restrict__ Wkp, __bf16* __restrict__ WkpT)
{
  int i = blockIdx.x*256 + threadIdx.x;   // 0..61439 (240 blocks, exact)
  int j = i >> 6, d = i & 63;             // coalesced read of Wkp
  WkpT[(size_t)d*KJ + j] = (__bf16)Wkp[i];
}

// ---- coords tail of output (f32) + stats/hist zeroing (block 192) ------------
__global__ __launch_bounds__(256) void emit_coords(
    const float* __restrict__ scd, const float* __restrict__ tcd,
    float* __restrict__ out, float* __restrict__ stats,
    unsigned int* __restrict__ hist)
{
  int b = blockIdx.x;
  int t = threadIdx.x;
  if (b == 192) {
    for (int i = t; i < 1024; i += 256) { stats[i] = 0.f; hist[i] = 0u; }
    return;
  }
  int i = b*256 + t;    // 0..49151
  out[i] = (i < NPTS*3) ? scd[i] : tcd[i - NPTS*3];
}

extern "C" void kernel_launch(void* const* d_in, const int* in_sizes, int n_in,
                              void* d_out, int out_size, void* d_ws, size_t ws_size,
                              hipStream_t stream)
{
  (void)in_sizes; (void)n_in; (void)out_size; (void)ws_size;
  const float* src   = (const float*)d_in[0];
  const float* tgt   = (const float*)d_in[1];
  const float* scd   = (const float*)d_in[2];
  const float* tcd   = (const float*)d_in[3];
  const float* W_in  = (const float*)d_in[4];
  const float* b_in  = (const float*)d_in[5];
  const float* kpts  = (const float*)d_in[6];
  const float* W_kp  = (const float*)d_in[7];
  const float* W_out = (const float*)d_in[8];
  const float* b_out = (const float*)d_in[9];
  const float* gamma = (const float*)d_in[10];
  const float* beta  = (const float*)d_in[11];

  // ---- workspace ----
  char* ws = (char*)d_ws;
  __bf16* h    = (__bf16*)ws;                       // 0..2 MB  [2][8192][64] bf16
  float* h2    = (float*)(ws + (4u<<20));           // 4..8 MB  [2][8192][64] f32
  short* fidx  = (short*)(ws + (8u<<20));           // 8..9 MB [16384][32] i16
  float* stats = (float*)(ws + (9u<<20));           // 4 KB
  __bf16* WkpT = (__bf16*)(ws + (9u<<20) + (64u<<10));  // 120 KB [64][960] bf16
  __bf16* WinF = (__bf16*)(ws + (9u<<20) + (256u<<10)); // 32 KB fragment-ordered
  // grid aux lives INSIDE the h2 region: dead before kpconv's first h2 write
  unsigned int* hist   = (unsigned int*)(ws + (4u<<20));            // 4 KB
  unsigned int* starts = (unsigned int*)(ws + (4u<<20) + (8u<<10)); // 2x520 u32
  unsigned int* cursor = (unsigned int*)(ws + (4u<<20) + (16u<<10));// 4 KB
  float4* sorted       = (float4*)(ws + (4u<<20) + (32u<<10));      // 256 KB

  float* yout = (float*)d_out;

  emit_coords<<<193, 256, 0, stream>>>(scd, tcd, yout + (size_t)2*NPTS*OUTC,
                                       stats, hist);
  wkp_cvt<<<240, 256, 0, stream>>>(W_kp, WkpT);
  win_cvt<<<64, 256, 0, stream>>>(W_in, WinF);
  grid_count<<<64, 256, 0, stream>>>(scd, tcd, hist);
  grid_scan<<<1, 512, 0, stream>>>(hist, starts, cursor);
  grid_scatter<<<64, 256, 0, stream>>>(scd, tcd, cursor, sorted);
  knn_grid<<<4096, 256, 0, stream>>>(scd, tcd, starts, sorted, fidx);
  conv_in_mfma<<<512, 128, 0, stream>>>(src, tgt, WinF, b_in, h);
  kpconv_fused<<<2048, 512, 0, stream>>>(scd, tcd, kpts, fidx, h, WkpT, h2);
  conv_out_bn<<<512, 512, 0, stream>>>(h2, W_out, b_out, yout, stats);
  bn_apply_k<<<16384, 256, 0, stream>>>(yout, stats, gamma, beta);
}